// Round 4
// baseline (4814.848 us; speedup 1.0000x reference)
//
#include <hip/hip_runtime.h>
#include <math.h>

#define N_ 32
#define S_ 197
#define D_ 768
#define H_ 12
#define L_ 8
#define FF_ 3072
#define MTOK (N_ * S_)      // 6304
#define ND (N_ * S_ * D_)   // 4841472

typedef __attribute__((ext_vector_type(8))) short short8x;
typedef __attribute__((ext_vector_type(4))) float floatx4;
typedef unsigned short ushort_t;
typedef unsigned int uint_t;

__device__ __forceinline__ ushort_t f2bf_rn(float x) {
  uint_t u = __float_as_uint(x);
  uint_t r = (u + 0x7fff + ((u >> 16) & 1)) >> 16;
  return (ushort_t)r;
}
__device__ __forceinline__ float bf2f(ushort_t h) {
  return __uint_as_float(((uint_t)h) << 16);
}

// async global->LDS, 16B per lane, dest = wave-uniform base + lane*16
__device__ __forceinline__ void gload16(const ushort_t* g, ushort_t* l) {
  __builtin_amdgcn_global_load_lds((const __attribute__((address_space(1))) void*)g,
                                   (__attribute__((address_space(3))) void*)l, 16, 0, 0);
}

// ---------------- patchify ----------------
__global__ __launch_bounds__(256) void patchify_kernel(const float* __restrict__ img,
                                                       ushort_t* __restrict__ phi,
                                                       ushort_t* __restrict__ plo) {
  int idx = blockIdx.x * 256 + threadIdx.x;
  if (idx >= 6272 * 768) return;
  int mp = idx / 768, kk = idx - mp * 768;
  int n = mp / 196, p = mp - n * 196;
  int py = p / 14, px = p - py * 14;
  int c = kk >> 8, r = kk & 255;
  int u = r >> 4, vv = r & 15;
  float val = img[((size_t)(n * 3 + c) * 224 + py * 16 + u) * 224 + px * 16 + vv];
  ushort_t hi = f2bf_rn(val);
  phi[idx] = hi;
  plo[idx] = f2bf_rn(val - bf2f(hi));
}

__global__ __launch_bounds__(256) void cls_init_kernel(const float* __restrict__ cls_tok,
                                                       const float* __restrict__ pos,
                                                       float* __restrict__ x) {
  int idx = blockIdx.x * 256 + threadIdx.x;  // 32*768
  int n = idx / 768, d = idx - n * 768;
  x[(size_t)n * S_ * D_ + d] = cls_tok[d] + pos[d];
}

// ---------------- weight transpose + hi/lo split ----------------
__global__ __launch_bounds__(256) void wconvert_kernel(const float* __restrict__ W,
                                                       ushort_t* __restrict__ Thi,
                                                       ushort_t* __restrict__ Tlo, int K, int N) {
  __shared__ float T[32][36];
  int n0 = blockIdx.x * 32, k0 = blockIdx.y * 32;
  int t = threadIdx.x;
  int r = t >> 3, c4 = (t & 7) * 4;
  float4 v = *(const float4*)&W[(size_t)(k0 + r) * N + n0 + c4];
  T[c4 + 0][r] = v.x;
  T[c4 + 1][r] = v.y;
  T[c4 + 2][r] = v.z;
  T[c4 + 3][r] = v.w;
  __syncthreads();
  ushort4 hi, lo;
  float a;
  a = T[r][c4 + 0]; hi.x = f2bf_rn(a); lo.x = f2bf_rn(a - bf2f(hi.x));
  a = T[r][c4 + 1]; hi.y = f2bf_rn(a); lo.y = f2bf_rn(a - bf2f(hi.y));
  a = T[r][c4 + 2]; hi.z = f2bf_rn(a); lo.z = f2bf_rn(a - bf2f(hi.z));
  a = T[r][c4 + 3]; hi.w = f2bf_rn(a); lo.w = f2bf_rn(a - bf2f(hi.w));
  size_t o = (size_t)(n0 + r) * K + k0 + c4;
  *(ushort4*)&Thi[o] = hi;
  *(ushort4*)&Tlo[o] = lo;
}

// ---------------- split-bf16 MFMA GEMM --------------
// grid: (mblocks, nblocks, KP). m-fastest natural order (XCD swizzle measured
// harmful on FETCH, neutral on time -> reverted).
// Staging: global_load_lds (16B/lane) into TRIPLE-buffered linear LDS with
// depth-2 prefetch and COUNTED vmcnt (T4): iter t stages tile t+2 (8 loads),
// computes tile t, then waits vmcnt(8) -> tile t+1 landed, tile t+2 still in
// flight across the barrier. Loads never drained in the main loop.
// Source-side chunk swizzle c ^= (row>>1)&3 (16B chunks), same XOR on ds_read
// addresses -> conflict-free b128 reads without padding.
// EPI_ATOM (KP=2): both K-halves unsafeAtomicAdd into Cf (z==0 adds bias).
#define EPI_PATCH 1
#define EPI_GELU 2
#define EPI_ATOM 3

template <int EPI, int KP>
__global__ __launch_bounds__(256) void gemm_mfma(
    const ushort_t* __restrict__ Ahi, const ushort_t* __restrict__ Alo,
    const ushort_t* __restrict__ Bhi, const ushort_t* __restrict__ Blo,
    const float* __restrict__ bias, float* __restrict__ Cf, ushort_t* __restrict__ Chi,
    ushort_t* __restrict__ Clo, int M, int K, int Nc, const float* __restrict__ pos) {
  __shared__ ushort_t As[3][2][128 * 32];  // [buf][plane], 8KB each -> 48KB
  __shared__ ushort_t Bs[3][2][128 * 32];  // 48KB
  int tid = threadIdx.x;
  int wave = tid >> 6, lane = tid & 63;
  int wr = (wave >> 1) * 64, wc = (wave & 1) * 64;
  int q = lane >> 4, l15 = lane & 15;
  int m0 = blockIdx.x * 128, n0 = blockIdx.y * 128;
  int kbeg = (KP > 1) ? blockIdx.z * (K / KP) : 0;
  int nt = (K / KP) >> 5;  // >= 24 for all uses

  floatx4 acc[4][4];
#pragma unroll
  for (int i = 0; i < 4; ++i)
#pragma unroll
    for (int j = 0; j < 4; ++j)
#pragma unroll
      for (int e = 0; e < 4; ++e) acc[i][j][e] = 0.f;

  // staging geometry: wave stages rows [wave*32, wave*32+32), 16 rows/instr
  int srow_in = lane >> 2;                 // 0..15 within instr
  int schunk = lane & 3;                   // 16B chunk within row
  // fragment read swizzle (row bits 1-2 come from l15 only)
  int csw = (q ^ ((l15 >> 1) & 3)) * 8;

  auto STAGE = [&](int buf, int k0) {
#pragma unroll
    for (int j = 0; j < 2; ++j) {
      int rbase = (wave << 5) + (j << 4);
      int r = rbase + srow_in;
      int cc = schunk ^ ((r >> 1) & 3);    // pre-swizzled source chunk
      int gm = m0 + r;
      if (gm > M - 1) gm = M - 1;
      size_t aoff = (size_t)gm * K + k0 + cc * 8;
      size_t boff = (size_t)(n0 + r) * K + k0 + cc * 8;
      gload16(&Ahi[aoff], &As[buf][0][rbase * 32]);
      gload16(&Alo[aoff], &As[buf][1][rbase * 32]);
      gload16(&Bhi[boff], &Bs[buf][0][rbase * 32]);
      gload16(&Blo[boff], &Bs[buf][1][rbase * 32]);
    }
  };

  // prologue: stage tiles 0 and 1 (8 loads each)
  STAGE(0, kbeg);
  STAGE(1, kbeg + 32);
  // tile 0 landed when <=8 outstanding (tile 1 still in flight)
  asm volatile("s_waitcnt vmcnt(8)" ::: "memory");
  __builtin_amdgcn_s_barrier();

  int cb = 0, sb = 2;  // compute buffer, stage buffer
  for (int t = 0; t < nt; ++t) {
    if (t + 2 < nt) STAGE(sb, kbeg + (t + 2) * 32);  // depth-2 prefetch

    short8x ah[4], al[4], bh[4], bl[4];
#pragma unroll
    for (int i = 0; i < 4; ++i) {
      int ao = (wr + i * 16 + l15) * 32 + csw;
      int bo = (wc + i * 16 + l15) * 32 + csw;
      ah[i] = *(const short8x*)&As[cb][0][ao];
      al[i] = *(const short8x*)&As[cb][1][ao];
      bh[i] = *(const short8x*)&Bs[cb][0][bo];
      bl[i] = *(const short8x*)&Bs[cb][1][bo];
    }
#pragma unroll
    for (int i = 0; i < 4; ++i)
#pragma unroll
      for (int j = 0; j < 4; ++j) {
        acc[i][j] = __builtin_amdgcn_mfma_f32_16x16x32_bf16(ah[i], bh[j], acc[i][j], 0, 0, 0);
        acc[i][j] = __builtin_amdgcn_mfma_f32_16x16x32_bf16(ah[i], bl[j], acc[i][j], 0, 0, 0);
        acc[i][j] = __builtin_amdgcn_mfma_f32_16x16x32_bf16(al[i], bh[j], acc[i][j], 0, 0, 0);
      }

    if (t + 2 < nt) {
      // tile t+1's 8 loads (issued last iter) done; tile t+2's 8 stay in flight
      asm volatile("s_waitcnt vmcnt(8)" ::: "memory");
      __builtin_amdgcn_s_barrier();
    } else if (t + 1 < nt) {
      // nothing staged this iter; drain the final tile's loads
      asm volatile("s_waitcnt vmcnt(0)" ::: "memory");
      __builtin_amdgcn_s_barrier();
    }
    cb = (cb == 2) ? 0 : cb + 1;
    sb = (sb == 2) ? 0 : sb + 1;
  }

#pragma unroll
  for (int i = 0; i < 4; ++i) {
#pragma unroll
    for (int j = 0; j < 4; ++j) {
      int col = n0 + wc + j * 16 + l15;
#pragma unroll
      for (int r4 = 0; r4 < 4; ++r4) {
        int gr = m0 + wr + i * 16 + q * 4 + r4;
        if (gr >= M) continue;
        if (EPI == EPI_ATOM) {
          float v = acc[i][j][r4];
          if (KP == 1 || blockIdx.z == 0) v += bias[col];
          unsafeAtomicAdd(&Cf[(size_t)gr * 768 + col], v);
        } else {
          float v = acc[i][j][r4] + bias[col];
          if (EPI == EPI_PATCH) {
            int n = gr / 196, t = gr - n * 196 + 1;
            Cf[((size_t)n * S_ + t) * 768 + col] = v + pos[(size_t)t * 768 + col];
          } else {  // EPI_GELU
            float g = 0.5f * v * (1.f + erff(v * 0.70710678118654752f));
            ushort_t hi = f2bf_rn(g);
            size_t o = (size_t)gr * FF_ + col;
            Chi[o] = hi;
            Clo[o] = f2bf_rn(g - bf2f(hi));
          }
        }
      }
    }
  }
}

// ---------------- LayerNorm -> bf16 hi/lo ----------------
__global__ __launch_bounds__(256) void ln_kernel(const float* __restrict__ x,
                                                 ushort_t* __restrict__ hhi,
                                                 ushort_t* __restrict__ hlo,
                                                 const float* __restrict__ w,
                                                 const float* __restrict__ b) {
  int tok = blockIdx.x * 4 + (threadIdx.x >> 6);
  int lane = threadIdx.x & 63;
  const float* xr = x + (size_t)tok * 768;
  float4 v[3];
  float s = 0.f, s2 = 0.f;
#pragma unroll
  for (int i = 0; i < 3; ++i) {
    v[i] = *(const float4*)&xr[i * 256 + lane * 4];
    s += v[i].x + v[i].y + v[i].z + v[i].w;
    s2 += v[i].x * v[i].x + v[i].y * v[i].y + v[i].z * v[i].z + v[i].w * v[i].w;
  }
#pragma unroll
  for (int m = 32; m > 0; m >>= 1) { s += __shfl_xor(s, m, 64); s2 += __shfl_xor(s2, m, 64); }
  float mu = s * (1.f / 768.f);
  float var = s2 * (1.f / 768.f) - mu * mu;
  float rs = rsqrtf(var + 1e-5f);
#pragma unroll
  for (int i = 0; i < 3; ++i) {
    float4 wv = *(const float4*)&w[i * 256 + lane * 4];
    float4 bv = *(const float4*)&b[i * 256 + lane * 4];
    float o0 = (v[i].x - mu) * rs * wv.x + bv.x;
    float o1 = (v[i].y - mu) * rs * wv.y + bv.y;
    float o2 = (v[i].z - mu) * rs * wv.z + bv.z;
    float o3 = (v[i].w - mu) * rs * wv.w + bv.w;
    ushort4 oh, ol;
    oh.x = f2bf_rn(o0); ol.x = f2bf_rn(o0 - bf2f(oh.x));
    oh.y = f2bf_rn(o1); ol.y = f2bf_rn(o1 - bf2f(oh.y));
    oh.z = f2bf_rn(o2); ol.z = f2bf_rn(o2 - bf2f(oh.z));
    oh.w = f2bf_rn(o3); ol.w = f2bf_rn(o3 - bf2f(oh.w));
    size_t o = (size_t)tok * 768 + i * 256 + lane * 4;
    *(ushort4*)&hhi[o] = oh;
    *(ushort4*)&hlo[o] = ol;
  }
}

// ---------------- QKV projection via MFMA: block = 128 tokens x head ----------------
#define KSTR 72

__global__ __launch_bounds__(256) void qkv_mfma(
    const ushort_t* __restrict__ hhi, const ushort_t* __restrict__ hlo,
    const float* __restrict__ Wq, const float* __restrict__ Wk, const float* __restrict__ Wv,
    const float* __restrict__ bq, const float* __restrict__ bk, const float* __restrict__ bv,
    ushort_t* __restrict__ qhi, ushort_t* __restrict__ qlo, ushort_t* __restrict__ khi,
    ushort_t* __restrict__ klo, ushort_t* __restrict__ vhi, ushort_t* __restrict__ vlo) {
  __shared__ ushort_t As[2][128 * KSTR];
  __shared__ ushort_t Ws[2][64 * KSTR];
  int tid = threadIdx.x;
  int wave = tid >> 6, lane = tid & 63;
  int q = lane >> 4, l15 = lane & 15;
  int m0 = blockIdx.x * 128, h = blockIdx.y;
  int wm = wave >> 1, wj = wave & 1;

#pragma unroll
  for (int p = 0; p < 2; ++p) {
    const ushort_t* src = p == 0 ? hhi : hlo;
#pragma unroll
    for (int it = 0; it < 4; ++it) {
      int idx = it * 256 + tid;
      int r = idx >> 3, c = idx & 7;
      int gm = m0 + r;
      if (gm > MTOK - 1) gm = MTOK - 1;
      *(uint4*)&As[p][r * KSTR + c * 8] = *(const uint4*)&src[(size_t)gm * 768 + h * 64 + c * 8];
    }
  }

  const float* Wmat[3] = {Wq + (size_t)h * 4096, Wk + (size_t)h * 4096, Wv + (size_t)h * 4096};
  const float* Bmat[3] = {bq + h * 64, bk + h * 64, bv + h * 64};
  ushort_t* Ohi[3] = {qhi, khi, vhi};
  ushort_t* Olo[3] = {qlo, klo, vlo};

  for (int mat = 0; mat < 3; ++mat) {
    __syncthreads();
#pragma unroll
    for (int it = 0; it < 4; ++it) {
      int idx = it * 256 + tid;
      int r = idx >> 4, c4 = (idx & 15) * 4;
      float4 wv = *(const float4*)&Wmat[mat][r * 64 + c4];
      float vals[4] = {wv.x, wv.y, wv.z, wv.w};
#pragma unroll
      for (int i = 0; i < 4; ++i) {
        ushort_t hi = f2bf_rn(vals[i]);
        Ws[0][(c4 + i) * KSTR + r] = hi;
        Ws[1][(c4 + i) * KSTR + r] = f2bf_rn(vals[i] - bf2f(hi));
      }
    }
    __syncthreads();

    floatx4 acc[4][2];
#pragma unroll
    for (int i = 0; i < 4; ++i)
#pragma unroll
      for (int j = 0; j < 2; ++j)
#pragma unroll
        for (int e = 0; e < 4; ++e) acc[i][j][e] = 0.f;

#pragma unroll
    for (int ks = 0; ks < 2; ++ks) {
      short8x bh[2], bl[2];
#pragma unroll
      for (int j = 0; j < 2; ++j) {
        int bb = (wj * 32 + j * 16 + l15) * KSTR + ks * 32 + q * 8;
        bh[j] = *(const short8x*)&Ws[0][bb];
        bl[j] = *(const short8x*)&Ws[1][bb];
      }
#pragma unroll
      for (int i = 0; i < 4; ++i) {
        int ab = (wm * 64 + i * 16 + l15) * KSTR + ks * 32 + q * 8;
        short8x ah = *(const short8x*)&As[0][ab];
        short8x al = *(const short8x*)&As[1][ab];
#pragma unroll
        for (int j = 0; j < 2; ++j) {
          acc[i][j] = __builtin_amdgcn_mfma_f32_16x16x32_bf16(ah, bh[j], acc[i][j], 0, 0, 0);
          acc[i][j] = __builtin_amdgcn_mfma_f32_16x16x32_bf16(ah, bl[j], acc[i][j], 0, 0, 0);
          acc[i][j] = __builtin_amdgcn_mfma_f32_16x16x32_bf16(al, bh[j], acc[i][j], 0, 0, 0);
        }
      }
    }
#pragma unroll
    for (int i = 0; i < 4; ++i)
#pragma unroll
      for (int j = 0; j < 2; ++j) {
        int col = wj * 32 + j * 16 + l15;
        float bias = Bmat[mat][col];
#pragma unroll
        for (int r = 0; r < 4; ++r) {
          int tok = m0 + wm * 64 + i * 16 + q * 4 + r;
          if (tok >= MTOK) continue;
          float v = acc[i][j][r] + bias;
          ushort_t hi = f2bf_rn(v);
          size_t o = (size_t)tok * 768 + h * 64 + col;
          Ohi[mat][o] = hi;
          Olo[mat][o] = f2bf_rn(v - bf2f(hi));
        }
      }
  }
}

// ---------------- MFMA flash attention ----------------
__global__ __launch_bounds__(256) void attn_mfma(
    const ushort_t* __restrict__ qhi, const ushort_t* __restrict__ qlo,
    const ushort_t* __restrict__ khi, const ushort_t* __restrict__ klo,
    const ushort_t* __restrict__ vhi, const ushort_t* __restrict__ vlo,
    float* __restrict__ X) {
  __shared__ ushort_t Qs[2][64 * KSTR];
  __shared__ ushort_t Ks[2][64 * KSTR];
  __shared__ ushort_t Vs[2][64 * KSTR];
  int tid = threadIdx.x;
  int wave = tid >> 6, lane = tid & 63;
  int q = lane >> 4, l15 = lane & 15;
  int qc = blockIdx.x, h = blockIdx.y, n = blockIdx.z;
  int q0 = qc * 64;
  int row0 = wave * 16;

#pragma unroll
  for (int p = 0; p < 2; ++p) {
    const ushort_t* src = p == 0 ? qhi : qlo;
#pragma unroll
    for (int it = 0; it < 2; ++it) {
      int idx = it * 256 + tid;
      int r = idx >> 3, c = idx & 7;
      int gr = q0 + r;
      if (gr > S_ - 1) gr = S_ - 1;
      *(uint4*)&Qs[p][r * KSTR + c * 8] =
          *(const uint4*)&src[((size_t)n * S_ + gr) * 768 + h * 64 + c * 8];
    }
  }
  __syncthreads();
  short8x qa_h[2], qa_l[2];
#pragma unroll
  for (int ks = 0; ks < 2; ++ks) {
    int ab = (row0 + l15) * KSTR + ks * 32 + q * 8;
    qa_h[ks] = *(const short8x*)&Qs[0][ab];
    qa_l[ks] = *(const short8x*)&Qs[1][ab];
  }

  float mrow[4], lrow[4];
  floatx4 oa[4];
#pragma unroll
  for (int r = 0; r < 4; ++r) { mrow[r] = -INFINITY; lrow[r] = 0.f; }
#pragma unroll
  for (int j = 0; j < 4; ++j)
#pragma unroll
    for (int e = 0; e < 4; ++e) oa[j][e] = 0.f;

  for (int t = 0; t < 4; ++t) {
    __syncthreads();
#pragma unroll
    for (int p = 0; p < 2; ++p) {
      const ushort_t* src = p == 0 ? khi : klo;
#pragma unroll
      for (int it = 0; it < 2; ++it) {
        int idx = it * 256 + tid;
        int r = idx >> 3, c = idx & 7;
        int gk = t * 64 + r;
        if (gk > S_ - 1) gk = S_ - 1;
        *(uint4*)&Ks[p][r * KSTR + c * 8] =
            *(const uint4*)&src[((size_t)n * S_ + gk) * 768 + h * 64 + c * 8];
      }
    }
    {
      int d = tid & 63, kg = tid >> 6;
#pragma unroll
      for (int p = 0; p < 2; ++p) {
        const ushort_t* src = p == 0 ? vhi : vlo;
#pragma unroll
        for (int k4 = 0; k4 < 4; ++k4) {
          ushort4 pk;
          ushort_t tmp[4];
#pragma unroll
          for (int i = 0; i < 4; ++i) {
            int gk = t * 64 + kg * 16 + k4 * 4 + i;
            if (gk > S_ - 1) gk = S_ - 1;
            tmp[i] = src[((size_t)n * S_ + gk) * 768 + h * 64 + d];
          }
          pk.x = tmp[0]; pk.y = tmp[1]; pk.z = tmp[2]; pk.w = tmp[3];
          *(ushort4*)&Vs[p][d * KSTR + kg * 16 + k4 * 4] = pk;
        }
      }
    }
    __syncthreads();

    floatx4 sc[4];
#pragma unroll
    for (int j = 0; j < 4; ++j) {
#pragma unroll
      for (int e = 0; e < 4; ++e) sc[j][e] = 0.f;
#pragma unroll
      for (int ks = 0; ks < 2; ++ks) {
        int bb = (j * 16 + l15) * KSTR + ks * 32 + q * 8;
        short8x kb_h = *(const short8x*)&Ks[0][bb];
        short8x kb_l = *(const short8x*)&Ks[1][bb];
        sc[j] = __builtin_amdgcn_mfma_f32_16x16x32_bf16(qa_h[ks], kb_h, sc[j], 0, 0, 0);
        sc[j] = __builtin_amdgcn_mfma_f32_16x16x32_bf16(qa_h[ks], kb_l, sc[j], 0, 0, 0);
        sc[j] = __builtin_amdgcn_mfma_f32_16x16x32_bf16(qa_l[ks], kb_h, sc[j], 0, 0, 0);
      }
    }
    __syncthreads();

    bool kvalid[4];
#pragma unroll
    for (int j = 0; j < 4; ++j) kvalid[j] = (t * 64 + j * 16 + l15) < S_;
#pragma unroll
    for (int r = 0; r < 4; ++r) {
      float sv[4];
#pragma unroll
      for (int j = 0; j < 4; ++j) sv[j] = kvalid[j] ? sc[j][r] * 0.125f : -INFINITY;
      float mx = fmaxf(fmaxf(sv[0], sv[1]), fmaxf(sv[2], sv[3]));
#pragma unroll
      for (int msk = 1; msk < 16; msk <<= 1) mx = fmaxf(mx, __shfl_xor(mx, msk, 64));
      float mn = fmaxf(mrow[r], mx);
      float al = expf(mrow[r] - mn);
      float p[4], ps = 0.f;
#pragma unroll
      for (int j = 0; j < 4; ++j) { p[j] = expf(sv[j] - mn); ps += p[j]; }
#pragma unroll
      for (int msk = 1; msk < 16; msk <<= 1) ps += __shfl_xor(ps, msk, 64);
      lrow[r] = lrow[r] * al + ps;
      mrow[r] = mn;
#pragma unroll
      for (int j = 0; j < 4; ++j) oa[j][r] *= al;
      int prow = (row0 + q * 4 + r) * KSTR;
#pragma unroll
      for (int j = 0; j < 4; ++j) {
        ushort_t phv = f2bf_rn(p[j]);
        Ks[0][prow + j * 16 + l15] = phv;
        Ks[1][prow + j * 16 + l15] = f2bf_rn(p[j] - bf2f(phv));
      }
    }

#pragma unroll
    for (int ks = 0; ks < 2; ++ks) {
      int ab = (row0 + l15) * KSTR + ks * 32 + q * 8;
      short8x pa_h = *(const short8x*)&Ks[0][ab];
      short8x pa_l = *(const short8x*)&Ks[1][ab];
#pragma unroll
      for (int j = 0; j < 4; ++j) {
        int bb = (j * 16 + l15) * KSTR + ks * 32 + q * 8;
        short8x vb_h = *(const short8x*)&Vs[0][bb];
        short8x vb_l = *(const short8x*)&Vs[1][bb];
        oa[j] = __builtin_amdgcn_mfma_f32_16x16x32_bf16(pa_h, vb_h, oa[j], 0, 0, 0);
        oa[j] = __builtin_amdgcn_mfma_f32_16x16x32_bf16(pa_h, vb_l, oa[j], 0, 0, 0);
        oa[j] = __builtin_amdgcn_mfma_f32_16x16x32_bf16(pa_l, vb_h, oa[j], 0, 0, 0);
      }
    }
  }

#pragma unroll
  for (int r = 0; r < 4; ++r) {
    int row = q0 + row0 + q * 4 + r;
    if (row >= S_) continue;
    float invl = 1.f / lrow[r];
#pragma unroll
    for (int j = 0; j < 4; ++j)
      X[((size_t)n * S_ + row) * 768 + h * 64 + j * 16 + l15] += oa[j][r] * invl;
  }
}

// ---------------- classifier head + softmax ----------------
__global__ __launch_bounds__(256) void head_kernel(const float* __restrict__ x,
                                                   const float* __restrict__ Wout,
                                                   const float* __restrict__ bout,
                                                   float* __restrict__ out) {
  __shared__ float cls[768];
  __shared__ float red[4];
  int n = blockIdx.x, tid = threadIdx.x;
  int w = tid >> 6, lane = tid & 63;
  for (int d = tid; d < 768; d += 256) cls[d] = x[(size_t)n * S_ * D_ + d];
  __syncthreads();
  int j0 = tid * 4;
  bool act = j0 < 1000;
  float a0 = 0.f, a1 = 0.f, a2 = 0.f, a3 = 0.f;
  if (act) {
    for (int kk = 0; kk < 768; ++kk) {
      float c = cls[kk];
      float4 wv = *(const float4*)&Wout[(size_t)kk * 1000 + j0];
      a0 += c * wv.x;
      a1 += c * wv.y;
      a2 += c * wv.z;
      a3 += c * wv.w;
    }
    a0 += bout[j0];
    a1 += bout[j0 + 1];
    a2 += bout[j0 + 2];
    a3 += bout[j0 + 3];
  }
  float mx = act ? fmaxf(fmaxf(a0, a1), fmaxf(a2, a3)) : -INFINITY;
#pragma unroll
  for (int m = 32; m > 0; m >>= 1) mx = fmaxf(mx, __shfl_xor(mx, m, 64));
  if (lane == 0) red[w] = mx;
  __syncthreads();
  mx = fmaxf(fmaxf(red[0], red[1]), fmaxf(red[2], red[3]));
  __syncthreads();
  float e0 = 0.f, e1 = 0.f, e2 = 0.f, e3 = 0.f, ss = 0.f;
  if (act) {
    e0 = expf(a0 - mx);
    e1 = expf(a1 - mx);
    e2 = expf(a2 - mx);
    e3 = expf(a3 - mx);
    ss = e0 + e1 + e2 + e3;
  }
#pragma unroll
  for (int m = 32; m > 0; m >>= 1) ss += __shfl_xor(ss, m, 64);
  if (lane == 0) red[w] = ss;
  __syncthreads();
  ss = red[0] + red[1] + red[2] + red[3];
  if (act) {
    float inv = 1.f / ss;
    out[(size_t)n * 1000 + j0] = e0 * inv;
    out[(size_t)n * 1000 + j0 + 1] = e1 * inv;
    out[(size_t)n * 1000 + j0 + 2] = e2 * inv;
    out[(size_t)n * 1000 + j0 + 3] = e3 * inv;
  }
}

extern "C" void kernel_launch(void* const* d_in, const int* in_sizes, int n_in, void* d_out,
                              int out_size, void* d_ws, size_t ws_size, hipStream_t stream) {
  const float* images = (const float*)d_in[0];
  const float* Wm = (const float*)d_in[1];
  const float* bm = (const float*)d_in[2];
  const float* cls_tok = (const float*)d_in[3];
  const float* pos_emb = (const float*)d_in[4];
  const float* ln1_w = (const float*)d_in[5];
  const float* ln1_b = (const float*)d_in[6];
  const float* Wq = (const float*)d_in[7];
  const float* bq = (const float*)d_in[8];
  const float* Wk = (const float*)d_in[9];
  const float* bk = (const float*)d_in[10];
  const float* Wv = (const float*)d_in[11];
  const float* bv = (const float*)d_in[12];
  const float* ln2_w = (const float*)d_in[13];
  const float* ln2_b = (const float*)d_in[14];
  const float* W1 = (const float*)d_in[15];
  const float* b1 = (const float*)d_in[16];
  const float* W2 = (const float*)d_in[17];
  const float* b2 = (const float*)d_in[18];
  const float* Wout = (const float*)d_in[19];
  const float* bout = (const float*)d_in[20];
  float* out = (float*)d_out;

  // --- workspace map (identical layout) ---
  char* base = (char*)d_ws;
  float* x = (float*)base;
  ushort_t* hhi = (ushort_t*)(base + (size_t)ND * 4);
  ushort_t* hlo = hhi + (size_t)ND;
  char* R = base + (size_t)ND * 8;
  ushort_t* qhi = (ushort_t*)R;
  ushort_t* qlo = qhi + (size_t)ND;
  ushort_t* khi = qlo + (size_t)ND;
  ushort_t* klo = khi + (size_t)ND;
  ushort_t* vhi = klo + (size_t)ND;
  ushort_t* vlo = vhi + (size_t)ND;
  ushort_t* ghi = (ushort_t*)R;
  ushort_t* glo = ghi + (size_t)MTOK * FF_;
  ushort_t* phi = (ushort_t*)R;
  ushort_t* plo = phi + (size_t)6272 * 768;
  char* WB = R + (size_t)MTOK * FF_ * 4;
  ushort_t* w1hi = (ushort_t*)WB;
  ushort_t* w1lo = w1hi + (size_t)768 * FF_;
  ushort_t* w2hi = w1lo + (size_t)768 * FF_;
  ushort_t* w2lo = w2hi + (size_t)768 * FF_;

  patchify_kernel<<<(6272 * 768 + 255) / 256, 256, 0, stream>>>(images, phi, plo);
  wconvert_kernel<<<dim3(24, 24), 256, 0, stream>>>(Wm, w1hi, w1lo, 768, 768);
  gemm_mfma<EPI_PATCH, 1><<<dim3(49, 6), 256, 0, stream>>>(phi, plo, w1hi, w1lo, bm, x,
                                                           nullptr, nullptr, 6272, 768, 768,
                                                           pos_emb);
  cls_init_kernel<<<(32 * 768) / 256, 256, 0, stream>>>(cls_tok, pos_emb, x);

  for (int l = 0; l < 8; ++l) {
    ln_kernel<<<MTOK / 4, 256, 0, stream>>>(x, hhi, hlo, ln1_w + l * 768, ln1_b + l * 768);
    qkv_mfma<<<dim3(50, 12), 256, 0, stream>>>(
        hhi, hlo, Wq + (size_t)l * 49152, Wk + (size_t)l * 49152, Wv + (size_t)l * 49152,
        bq + l * 768, bk + l * 768, bv + l * 768, qhi, qlo, khi, klo, vhi, vlo);
    attn_mfma<<<dim3(4, 12, 32), 256, 0, stream>>>(qhi, qlo, khi, klo, vhi, vlo, x);
    ln_kernel<<<MTOK / 4, 256, 0, stream>>>(x, hhi, hlo, ln2_w + l * 768, ln2_b + l * 768);
    wconvert_kernel<<<dim3(96, 24), 256, 0, stream>>>(W1 + (size_t)l * 768 * FF_, w1hi, w1lo,
                                                      768, FF_);
    gemm_mfma<EPI_GELU, 1><<<dim3(50, 24), 256, 0, stream>>>(hhi, hlo, w1hi, w1lo, b1 + l * FF_,
                                                             nullptr, ghi, glo, MTOK, 768, FF_,
                                                             nullptr);
    wconvert_kernel<<<dim3(24, 96), 256, 0, stream>>>(W2 + (size_t)l * FF_ * 768, w2hi, w2lo,
                                                      FF_, 768);
    // FC2 split-K=2: both halves atomically accumulate into x (z==0 adds bias)
    gemm_mfma<EPI_ATOM, 2><<<dim3(50, 6, 2), 256, 0, stream>>>(ghi, glo, w2hi, w2lo,
                                                               b2 + l * 768, x, nullptr,
                                                               nullptr, MTOK, FF_, 768,
                                                               nullptr);
  }
  head_kernel<<<32, 256, 0, stream>>>(x, Wout, bout, out);
}

// Round 5
// 3761.250 us; speedup vs baseline: 1.2801x; 1.2801x over previous
//
#include <hip/hip_runtime.h>
#include <math.h>

#define N_ 32
#define S_ 197
#define D_ 768
#define H_ 12
#define L_ 8
#define FF_ 3072
#define MTOK (N_ * S_)      // 6304
#define ND (N_ * S_ * D_)   // 4841472
#define VT_ (12 * 64 * 32 * 256)  // vT[h][d][n][256] elements per plane

typedef __attribute__((ext_vector_type(8))) short short8x;
typedef __attribute__((ext_vector_type(4))) float floatx4;
typedef unsigned short ushort_t;
typedef unsigned int uint_t;

__device__ __forceinline__ ushort_t f2bf_rn(float x) {
  uint_t u = __float_as_uint(x);
  uint_t r = (u + 0x7fff + ((u >> 16) & 1)) >> 16;
  return (ushort_t)r;
}
__device__ __forceinline__ float bf2f(ushort_t h) {
  return __uint_as_float(((uint_t)h) << 16);
}

// async global->LDS, 16B per lane, dest = wave-uniform base + lane*16
__device__ __forceinline__ void gload16(const ushort_t* g, ushort_t* l) {
  __builtin_amdgcn_global_load_lds((const __attribute__((address_space(1))) void*)g,
                                   (__attribute__((address_space(3))) void*)l, 16, 0, 0);
}

// ---------------- patchify ----------------
__global__ __launch_bounds__(256) void patchify_kernel(const float* __restrict__ img,
                                                       ushort_t* __restrict__ phi,
                                                       ushort_t* __restrict__ plo) {
  int idx = blockIdx.x * 256 + threadIdx.x;
  if (idx >= 6272 * 768) return;
  int mp = idx / 768, kk = idx - mp * 768;
  int n = mp / 196, p = mp - n * 196;
  int py = p / 14, px = p - py * 14;
  int c = kk >> 8, r = kk & 255;
  int u = r >> 4, vv = r & 15;
  float val = img[((size_t)(n * 3 + c) * 224 + py * 16 + u) * 224 + px * 16 + vv];
  ushort_t hi = f2bf_rn(val);
  phi[idx] = hi;
  plo[idx] = f2bf_rn(val - bf2f(hi));
}

__global__ __launch_bounds__(256) void cls_init_kernel(const float* __restrict__ cls_tok,
                                                       const float* __restrict__ pos,
                                                       float* __restrict__ x) {
  int idx = blockIdx.x * 256 + threadIdx.x;  // 32*768
  int n = idx / 768, d = idx - n * 768;
  x[(size_t)n * S_ * D_ + d] = cls_tok[d] + pos[d];
}

// ---------------- weight transpose + hi/lo split ----------------
__global__ __launch_bounds__(256) void wconvert_kernel(const float* __restrict__ W,
                                                       ushort_t* __restrict__ Thi,
                                                       ushort_t* __restrict__ Tlo, int K, int N) {
  __shared__ float T[32][36];
  int n0 = blockIdx.x * 32, k0 = blockIdx.y * 32;
  int t = threadIdx.x;
  int r = t >> 3, c4 = (t & 7) * 4;
  float4 v = *(const float4*)&W[(size_t)(k0 + r) * N + n0 + c4];
  T[c4 + 0][r] = v.x;
  T[c4 + 1][r] = v.y;
  T[c4 + 2][r] = v.z;
  T[c4 + 3][r] = v.w;
  __syncthreads();
  ushort4 hi, lo;
  float a;
  a = T[r][c4 + 0]; hi.x = f2bf_rn(a); lo.x = f2bf_rn(a - bf2f(hi.x));
  a = T[r][c4 + 1]; hi.y = f2bf_rn(a); lo.y = f2bf_rn(a - bf2f(hi.y));
  a = T[r][c4 + 2]; hi.z = f2bf_rn(a); lo.z = f2bf_rn(a - bf2f(hi.z));
  a = T[r][c4 + 3]; hi.w = f2bf_rn(a); lo.w = f2bf_rn(a - bf2f(hi.w));
  size_t o = (size_t)(n0 + r) * K + k0 + c4;
  *(ushort4*)&Thi[o] = hi;
  *(ushort4*)&Tlo[o] = lo;
}

// ---------------- QKV weight pre-convert: W[h][k][col] -> Wt[mat][h][col][k] hi/lo ---
__global__ __launch_bounds__(256) void qkvw_convert(const float* __restrict__ Wq,
                                                    const float* __restrict__ Wk,
                                                    const float* __restrict__ Wv,
                                                    ushort_t* __restrict__ wthi,
                                                    ushort_t* __restrict__ wtlo) {
  __shared__ float T[64][65];
  int h = blockIdx.x, mat = blockIdx.y;
  const float* W = (mat == 0 ? Wq : mat == 1 ? Wk : Wv) + (size_t)h * 4096;
  int tid = threadIdx.x;
  int r = tid >> 2, c0 = (tid & 3) * 16;
#pragma unroll
  for (int i = 0; i < 4; ++i) {
    float4 v = *(const float4*)&W[r * 64 + c0 + i * 4];
    T[c0 + i * 4 + 0][r] = v.x;
    T[c0 + i * 4 + 1][r] = v.y;
    T[c0 + i * 4 + 2][r] = v.z;
    T[c0 + i * 4 + 3][r] = v.w;
  }
  __syncthreads();
  size_t base = (((size_t)mat * 12 + h) * 64 + r) * 64 + c0;  // Wt[col=r][k]
#pragma unroll
  for (int i = 0; i < 4; ++i) {
    ushort4 hi4, lo4;
    float a;
    a = T[r][c0 + i * 4 + 0]; hi4.x = f2bf_rn(a); lo4.x = f2bf_rn(a - bf2f(hi4.x));
    a = T[r][c0 + i * 4 + 1]; hi4.y = f2bf_rn(a); lo4.y = f2bf_rn(a - bf2f(hi4.y));
    a = T[r][c0 + i * 4 + 2]; hi4.z = f2bf_rn(a); lo4.z = f2bf_rn(a - bf2f(hi4.z));
    a = T[r][c0 + i * 4 + 3]; hi4.w = f2bf_rn(a); lo4.w = f2bf_rn(a - bf2f(hi4.w));
    *(ushort4*)&wthi[base + i * 4] = hi4;
    *(ushort4*)&wtlo[base + i * 4] = lo4;
  }
}

// ---------------- split-bf16 MFMA GEMM (R1 structure: best measured) --------------
// grid: (mblocks, nblocks, KP). m-fastest for B-slab L2 reuse.
// Staging: global_load_lds (16B/lane) into double-buffered linear LDS
// (2-phase prefetch: STAGE(t+1) -> compute(t) -> vmcnt(0) -> s_barrier; 64KB ->
// 2 blocks/CU whose mutual overlap hides load latency — triple-buffer measured worse).
// Source-side chunk swizzle c ^= (row>>1)&3 (16B chunks), same XOR on ds_read
// addresses -> conflict-free b128 reads without padding.
// EPI_ATOM (KP=2): both K-halves unsafeAtomicAdd into Cf (z==0 adds bias).
#define EPI_PATCH 1
#define EPI_GELU 2
#define EPI_ATOM 3

template <int EPI, int KP>
__global__ __launch_bounds__(256) void gemm_mfma(
    const ushort_t* __restrict__ Ahi, const ushort_t* __restrict__ Alo,
    const ushort_t* __restrict__ Bhi, const ushort_t* __restrict__ Blo,
    const float* __restrict__ bias, float* __restrict__ Cf, ushort_t* __restrict__ Chi,
    ushort_t* __restrict__ Clo, int M, int K, int Nc, const float* __restrict__ pos) {
  __shared__ ushort_t As[2][2][128 * 32];  // [buf][plane], 8KB each
  __shared__ ushort_t Bs[2][2][128 * 32];
  int tid = threadIdx.x;
  int wave = tid >> 6, lane = tid & 63;
  int wr = (wave >> 1) * 64, wc = (wave & 1) * 64;
  int q = lane >> 4, l15 = lane & 15;
  int m0 = blockIdx.x * 128, n0 = blockIdx.y * 128;
  int kbeg = (KP > 1) ? blockIdx.z * (K / KP) : 0;
  int nt = (K / KP) >> 5;

  floatx4 acc[4][4];
#pragma unroll
  for (int i = 0; i < 4; ++i)
#pragma unroll
    for (int j = 0; j < 4; ++j)
#pragma unroll
      for (int e = 0; e < 4; ++e) acc[i][j][e] = 0.f;

  int srow_in = lane >> 2;
  int schunk = lane & 3;
  int csw = (q ^ ((l15 >> 1) & 3)) * 8;

  auto STAGE = [&](int buf, int k0) {
#pragma unroll
    for (int j = 0; j < 2; ++j) {
      int rbase = (wave << 5) + (j << 4);
      int r = rbase + srow_in;
      int cc = schunk ^ ((r >> 1) & 3);
      int gm = m0 + r;
      if (gm > M - 1) gm = M - 1;
      size_t aoff = (size_t)gm * K + k0 + cc * 8;
      size_t boff = (size_t)(n0 + r) * K + k0 + cc * 8;
      gload16(&Ahi[aoff], &As[buf][0][rbase * 32]);
      gload16(&Alo[aoff], &As[buf][1][rbase * 32]);
      gload16(&Bhi[boff], &Bs[buf][0][rbase * 32]);
      gload16(&Blo[boff], &Bs[buf][1][rbase * 32]);
    }
  };

  STAGE(0, kbeg);
  asm volatile("s_waitcnt vmcnt(0)" ::: "memory");
  __builtin_amdgcn_s_barrier();

  int cur = 0;
  for (int t = 0; t < nt; ++t) {
    if (t + 1 < nt) STAGE(cur ^ 1, kbeg + (t + 1) * 32);

    short8x ah[4], al[4], bh[4], bl[4];
#pragma unroll
    for (int i = 0; i < 4; ++i) {
      int ao = (wr + i * 16 + l15) * 32 + csw;
      int bo = (wc + i * 16 + l15) * 32 + csw;
      ah[i] = *(const short8x*)&As[cur][0][ao];
      al[i] = *(const short8x*)&As[cur][1][ao];
      bh[i] = *(const short8x*)&Bs[cur][0][bo];
      bl[i] = *(const short8x*)&Bs[cur][1][bo];
    }
#pragma unroll
    for (int i = 0; i < 4; ++i)
#pragma unroll
      for (int j = 0; j < 4; ++j) {
        acc[i][j] = __builtin_amdgcn_mfma_f32_16x16x32_bf16(ah[i], bh[j], acc[i][j], 0, 0, 0);
        acc[i][j] = __builtin_amdgcn_mfma_f32_16x16x32_bf16(ah[i], bl[j], acc[i][j], 0, 0, 0);
        acc[i][j] = __builtin_amdgcn_mfma_f32_16x16x32_bf16(al[i], bh[j], acc[i][j], 0, 0, 0);
      }
    asm volatile("s_waitcnt vmcnt(0)" ::: "memory");
    __builtin_amdgcn_s_barrier();
    cur ^= 1;
  }

#pragma unroll
  for (int i = 0; i < 4; ++i) {
#pragma unroll
    for (int j = 0; j < 4; ++j) {
      int col = n0 + wc + j * 16 + l15;
#pragma unroll
      for (int r4 = 0; r4 < 4; ++r4) {
        int gr = m0 + wr + i * 16 + q * 4 + r4;
        if (gr >= M) continue;
        if (EPI == EPI_ATOM) {
          float v = acc[i][j][r4];
          if (KP == 1 || blockIdx.z == 0) v += bias[col];
          unsafeAtomicAdd(&Cf[(size_t)gr * 768 + col], v);
        } else {
          float v = acc[i][j][r4] + bias[col];
          if (EPI == EPI_PATCH) {
            int n = gr / 196, t = gr - n * 196 + 1;
            Cf[((size_t)n * S_ + t) * 768 + col] = v + pos[(size_t)t * 768 + col];
          } else {  // EPI_GELU
            float g = 0.5f * v * (1.f + erff(v * 0.70710678118654752f));
            ushort_t hi = f2bf_rn(g);
            size_t o = (size_t)gr * FF_ + col;
            Chi[o] = hi;
            Clo[o] = f2bf_rn(g - bf2f(hi));
          }
        }
      }
    }
  }
}

// ---------------- LayerNorm -> bf16 hi/lo ----------------
__global__ __launch_bounds__(256) void ln_kernel(const float* __restrict__ x,
                                                 ushort_t* __restrict__ hhi,
                                                 ushort_t* __restrict__ hlo,
                                                 const float* __restrict__ w,
                                                 const float* __restrict__ b) {
  int tok = blockIdx.x * 4 + (threadIdx.x >> 6);
  int lane = threadIdx.x & 63;
  const float* xr = x + (size_t)tok * 768;
  float4 v[3];
  float s = 0.f, s2 = 0.f;
#pragma unroll
  for (int i = 0; i < 3; ++i) {
    v[i] = *(const float4*)&xr[i * 256 + lane * 4];
    s += v[i].x + v[i].y + v[i].z + v[i].w;
    s2 += v[i].x * v[i].x + v[i].y * v[i].y + v[i].z * v[i].z + v[i].w * v[i].w;
  }
#pragma unroll
  for (int m = 32; m > 0; m >>= 1) { s += __shfl_xor(s, m, 64); s2 += __shfl_xor(s2, m, 64); }
  float mu = s * (1.f / 768.f);
  float var = s2 * (1.f / 768.f) - mu * mu;
  float rs = rsqrtf(var + 1e-5f);
#pragma unroll
  for (int i = 0; i < 3; ++i) {
    float4 wv = *(const float4*)&w[i * 256 + lane * 4];
    float4 bv = *(const float4*)&b[i * 256 + lane * 4];
    float o0 = (v[i].x - mu) * rs * wv.x + bv.x;
    float o1 = (v[i].y - mu) * rs * wv.y + bv.y;
    float o2 = (v[i].z - mu) * rs * wv.z + bv.z;
    float o3 = (v[i].w - mu) * rs * wv.w + bv.w;
    ushort4 oh, ol;
    oh.x = f2bf_rn(o0); ol.x = f2bf_rn(o0 - bf2f(oh.x));
    oh.y = f2bf_rn(o1); ol.y = f2bf_rn(o1 - bf2f(oh.y));
    oh.z = f2bf_rn(o2); ol.z = f2bf_rn(o2 - bf2f(oh.z));
    oh.w = f2bf_rn(o3); ol.w = f2bf_rn(o3 - bf2f(oh.w));
    size_t o = (size_t)tok * 768 + i * 256 + lane * 4;
    *(ushort4*)&hhi[o] = oh;
    *(ushort4*)&hlo[o] = ol;
  }
}

// ---------------- QKV projection via MFMA: block = 128 tokens x head ----------------
// W fragments read DIRECTLY from pre-converted Wt[mat][h][col][k] (global->reg,
// no W-LDS, single barrier). V written pre-transposed to vT[h][d][n][256].
#define KSTR 72

__global__ __launch_bounds__(256) void qkv_mfma(
    const ushort_t* __restrict__ hhi, const ushort_t* __restrict__ hlo,
    const ushort_t* __restrict__ wthi, const ushort_t* __restrict__ wtlo,
    const float* __restrict__ bq, const float* __restrict__ bk, const float* __restrict__ bv,
    ushort_t* __restrict__ qhi, ushort_t* __restrict__ qlo, ushort_t* __restrict__ khi,
    ushort_t* __restrict__ klo, ushort_t* __restrict__ vthi, ushort_t* __restrict__ vtlo) {
  __shared__ ushort_t As[2][128 * KSTR];
  int tid = threadIdx.x;
  int wave = tid >> 6, lane = tid & 63;
  int q = lane >> 4, l15 = lane & 15;
  int m0 = blockIdx.x * 128, h = blockIdx.y;
  int wm = wave >> 1, wj = wave & 1;

#pragma unroll
  for (int p = 0; p < 2; ++p) {
    const ushort_t* src = p == 0 ? hhi : hlo;
#pragma unroll
    for (int it = 0; it < 4; ++it) {
      int idx = it * 256 + tid;
      int r = idx >> 3, c = idx & 7;
      int gm = m0 + r;
      if (gm > MTOK - 1) gm = MTOK - 1;
      *(uint4*)&As[p][r * KSTR + c * 8] = *(const uint4*)&src[(size_t)gm * 768 + h * 64 + c * 8];
    }
  }
  __syncthreads();

  const float* Bmat[3] = {bq + h * 64, bk + h * 64, bv + h * 64};
  ushort_t* Ohi[2] = {qhi, khi};
  ushort_t* Olo[2] = {qlo, klo};

  for (int mat = 0; mat < 3; ++mat) {
    const ushort_t* wh = wthi + ((size_t)mat * 12 + h) * 4096;
    const ushort_t* wl = wtlo + ((size_t)mat * 12 + h) * 4096;
    short8x bh[2][2], bl[2][2];  // [ks][j]
#pragma unroll
    for (int ks = 0; ks < 2; ++ks)
#pragma unroll
      for (int j = 0; j < 2; ++j) {
        int wo = (wj * 32 + j * 16 + l15) * 64 + ks * 32 + q * 8;
        bh[ks][j] = *(const short8x*)&wh[wo];
        bl[ks][j] = *(const short8x*)&wl[wo];
      }

    floatx4 acc[4][2];
#pragma unroll
    for (int i = 0; i < 4; ++i)
#pragma unroll
      for (int j = 0; j < 2; ++j)
#pragma unroll
        for (int e = 0; e < 4; ++e) acc[i][j][e] = 0.f;

#pragma unroll
    for (int ks = 0; ks < 2; ++ks) {
#pragma unroll
      for (int i = 0; i < 4; ++i) {
        int ab = (wm * 64 + i * 16 + l15) * KSTR + ks * 32 + q * 8;
        short8x ah = *(const short8x*)&As[0][ab];
        short8x al = *(const short8x*)&As[1][ab];
#pragma unroll
        for (int j = 0; j < 2; ++j) {
          acc[i][j] = __builtin_amdgcn_mfma_f32_16x16x32_bf16(ah, bh[ks][j], acc[i][j], 0, 0, 0);
          acc[i][j] = __builtin_amdgcn_mfma_f32_16x16x32_bf16(ah, bl[ks][j], acc[i][j], 0, 0, 0);
          acc[i][j] = __builtin_amdgcn_mfma_f32_16x16x32_bf16(al, bh[ks][j], acc[i][j], 0, 0, 0);
        }
      }
    }
#pragma unroll
    for (int i = 0; i < 4; ++i)
#pragma unroll
      for (int j = 0; j < 2; ++j) {
        int col = wj * 32 + j * 16 + l15;
        float bias = Bmat[mat][col];
#pragma unroll
        for (int r = 0; r < 4; ++r) {
          int tok = m0 + wm * 64 + i * 16 + q * 4 + r;
          if (tok >= MTOK) continue;
          float v = acc[i][j][r] + bias;
          ushort_t hi = f2bf_rn(v);
          ushort_t lo = f2bf_rn(v - bf2f(hi));
          if (mat < 2) {
            size_t o = (size_t)tok * 768 + h * 64 + col;
            Ohi[mat][o] = hi;
            Olo[mat][o] = lo;
          } else {
            int n_img = tok / 197, s = tok - n_img * 197;
            size_t o = (((size_t)h * 64 + col) * 32 + n_img) * 256 + s;
            vthi[o] = hi;
            vtlo[o] = lo;
          }
        }
      }
  }
}

// ---------------- MFMA flash attention ----------------
// V staged from pre-transposed vT[h][d][n][256] via uint4 loads + b128 LDS
// writes (was: 32 scalar global loads/thread/tile). Pad s>=197 is zeroed once
// host-side (memset) -> masked keys contribute p=0 * 0.0.
__global__ __launch_bounds__(256) void attn_mfma(
    const ushort_t* __restrict__ qhi, const ushort_t* __restrict__ qlo,
    const ushort_t* __restrict__ khi, const ushort_t* __restrict__ klo,
    const ushort_t* __restrict__ vthi, const ushort_t* __restrict__ vtlo,
    float* __restrict__ X) {
  __shared__ ushort_t Qs[2][64 * KSTR];
  __shared__ ushort_t Ks[2][64 * KSTR];
  __shared__ ushort_t Vs[2][64 * KSTR];
  int tid = threadIdx.x;
  int wave = tid >> 6, lane = tid & 63;
  int q = lane >> 4, l15 = lane & 15;
  int qc = blockIdx.x, h = blockIdx.y, n = blockIdx.z;
  int q0 = qc * 64;
  int row0 = wave * 16;

#pragma unroll
  for (int p = 0; p < 2; ++p) {
    const ushort_t* src = p == 0 ? qhi : qlo;
#pragma unroll
    for (int it = 0; it < 2; ++it) {
      int idx = it * 256 + tid;
      int r = idx >> 3, c = idx & 7;
      int gr = q0 + r;
      if (gr > S_ - 1) gr = S_ - 1;
      *(uint4*)&Qs[p][r * KSTR + c * 8] =
          *(const uint4*)&src[((size_t)n * S_ + gr) * 768 + h * 64 + c * 8];
    }
  }
  __syncthreads();
  short8x qa_h[2], qa_l[2];
#pragma unroll
  for (int ks = 0; ks < 2; ++ks) {
    int ab = (row0 + l15) * KSTR + ks * 32 + q * 8;
    qa_h[ks] = *(const short8x*)&Qs[0][ab];
    qa_l[ks] = *(const short8x*)&Qs[1][ab];
  }

  float mrow[4], lrow[4];
  floatx4 oa[4];
#pragma unroll
  for (int r = 0; r < 4; ++r) { mrow[r] = -INFINITY; lrow[r] = 0.f; }
#pragma unroll
  for (int j = 0; j < 4; ++j)
#pragma unroll
    for (int e = 0; e < 4; ++e) oa[j][e] = 0.f;

  for (int t = 0; t < 4; ++t) {
    __syncthreads();
#pragma unroll
    for (int p = 0; p < 2; ++p) {
      const ushort_t* src = p == 0 ? khi : klo;
#pragma unroll
      for (int it = 0; it < 2; ++it) {
        int idx = it * 256 + tid;
        int r = idx >> 3, c = idx & 7;
        int gk = t * 64 + r;
        if (gk > S_ - 1) gk = S_ - 1;
        *(uint4*)&Ks[p][r * KSTR + c * 8] =
            *(const uint4*)&src[((size_t)n * S_ + gk) * 768 + h * 64 + c * 8];
      }
    }
    {
      int d = tid >> 2, kc = tid & 3;
#pragma unroll
      for (int p = 0; p < 2; ++p) {
        const ushort_t* src = p == 0 ? vthi : vtlo;
#pragma unroll
        for (int it = 0; it < 2; ++it) {
          int k0 = it * 32 + kc * 8;
          *(uint4*)&Vs[p][d * KSTR + k0] =
              *(const uint4*)&src[(((size_t)h * 64 + d) * 32 + n) * 256 + t * 64 + k0];
        }
      }
    }
    __syncthreads();

    floatx4 sc[4];
#pragma unroll
    for (int j = 0; j < 4; ++j) {
#pragma unroll
      for (int e = 0; e < 4; ++e) sc[j][e] = 0.f;
#pragma unroll
      for (int ks = 0; ks < 2; ++ks) {
        int bb = (j * 16 + l15) * KSTR + ks * 32 + q * 8;
        short8x kb_h = *(const short8x*)&Ks[0][bb];
        short8x kb_l = *(const short8x*)&Ks[1][bb];
        sc[j] = __builtin_amdgcn_mfma_f32_16x16x32_bf16(qa_h[ks], kb_h, sc[j], 0, 0, 0);
        sc[j] = __builtin_amdgcn_mfma_f32_16x16x32_bf16(qa_h[ks], kb_l, sc[j], 0, 0, 0);
        sc[j] = __builtin_amdgcn_mfma_f32_16x16x32_bf16(qa_l[ks], kb_h, sc[j], 0, 0, 0);
      }
    }
    __syncthreads();

    bool kvalid[4];
#pragma unroll
    for (int j = 0; j < 4; ++j) kvalid[j] = (t * 64 + j * 16 + l15) < S_;
#pragma unroll
    for (int r = 0; r < 4; ++r) {
      float sv[4];
#pragma unroll
      for (int j = 0; j < 4; ++j) sv[j] = kvalid[j] ? sc[j][r] * 0.125f : -INFINITY;
      float mx = fmaxf(fmaxf(sv[0], sv[1]), fmaxf(sv[2], sv[3]));
#pragma unroll
      for (int msk = 1; msk < 16; msk <<= 1) mx = fmaxf(mx, __shfl_xor(mx, msk, 64));
      float mn = fmaxf(mrow[r], mx);
      float al = expf(mrow[r] - mn);
      float p[4], ps = 0.f;
#pragma unroll
      for (int j = 0; j < 4; ++j) { p[j] = expf(sv[j] - mn); ps += p[j]; }
#pragma unroll
      for (int msk = 1; msk < 16; msk <<= 1) ps += __shfl_xor(ps, msk, 64);
      lrow[r] = lrow[r] * al + ps;
      mrow[r] = mn;
#pragma unroll
      for (int j = 0; j < 4; ++j) oa[j][r] *= al;
      int prow = (row0 + q * 4 + r) * KSTR;
#pragma unroll
      for (int j = 0; j < 4; ++j) {
        ushort_t phv = f2bf_rn(p[j]);
        Ks[0][prow + j * 16 + l15] = phv;
        Ks[1][prow + j * 16 + l15] = f2bf_rn(p[j] - bf2f(phv));
      }
    }

#pragma unroll
    for (int ks = 0; ks < 2; ++ks) {
      int ab = (row0 + l15) * KSTR + ks * 32 + q * 8;
      short8x pa_h = *(const short8x*)&Ks[0][ab];
      short8x pa_l = *(const short8x*)&Ks[1][ab];
#pragma unroll
      for (int j = 0; j < 4; ++j) {
        int bb = (j * 16 + l15) * KSTR + ks * 32 + q * 8;
        short8x vb_h = *(const short8x*)&Vs[0][bb];
        short8x vb_l = *(const short8x*)&Vs[1][bb];
        oa[j] = __builtin_amdgcn_mfma_f32_16x16x32_bf16(pa_h, vb_h, oa[j], 0, 0, 0);
        oa[j] = __builtin_amdgcn_mfma_f32_16x16x32_bf16(pa_h, vb_l, oa[j], 0, 0, 0);
        oa[j] = __builtin_amdgcn_mfma_f32_16x16x32_bf16(pa_l, vb_h, oa[j], 0, 0, 0);
      }
    }
  }

#pragma unroll
  for (int r = 0; r < 4; ++r) {
    int row = q0 + row0 + q * 4 + r;
    if (row >= S_) continue;
    float invl = 1.f / lrow[r];
#pragma unroll
    for (int j = 0; j < 4; ++j)
      X[((size_t)n * S_ + row) * 768 + h * 64 + j * 16 + l15] += oa[j][r] * invl;
  }
}

// ---------------- classifier head + softmax ----------------
__global__ __launch_bounds__(256) void head_kernel(const float* __restrict__ x,
                                                   const float* __restrict__ Wout,
                                                   const float* __restrict__ bout,
                                                   float* __restrict__ out) {
  __shared__ float cls[768];
  __shared__ float red[4];
  int n = blockIdx.x, tid = threadIdx.x;
  int w = tid >> 6, lane = tid & 63;
  for (int d = tid; d < 768; d += 256) cls[d] = x[(size_t)n * S_ * D_ + d];
  __syncthreads();
  int j0 = tid * 4;
  bool act = j0 < 1000;
  float a0 = 0.f, a1 = 0.f, a2 = 0.f, a3 = 0.f;
  if (act) {
    for (int kk = 0; kk < 768; ++kk) {
      float c = cls[kk];
      float4 wv = *(const float4*)&Wout[(size_t)kk * 1000 + j0];
      a0 += c * wv.x;
      a1 += c * wv.y;
      a2 += c * wv.z;
      a3 += c * wv.w;
    }
    a0 += bout[j0];
    a1 += bout[j0 + 1];
    a2 += bout[j0 + 2];
    a3 += bout[j0 + 3];
  }
  float mx = act ? fmaxf(fmaxf(a0, a1), fmaxf(a2, a3)) : -INFINITY;
#pragma unroll
  for (int m = 32; m > 0; m >>= 1) mx = fmaxf(mx, __shfl_xor(mx, m, 64));
  if (lane == 0) red[w] = mx;
  __syncthreads();
  mx = fmaxf(fmaxf(red[0], red[1]), fmaxf(red[2], red[3]));
  __syncthreads();
  float e0 = 0.f, e1 = 0.f, e2 = 0.f, e3 = 0.f, ss = 0.f;
  if (act) {
    e0 = expf(a0 - mx);
    e1 = expf(a1 - mx);
    e2 = expf(a2 - mx);
    e3 = expf(a3 - mx);
    ss = e0 + e1 + e2 + e3;
  }
#pragma unroll
  for (int m = 32; m > 0; m >>= 1) ss += __shfl_xor(ss, m, 64);
  if (lane == 0) red[w] = ss;
  __syncthreads();
  ss = red[0] + red[1] + red[2] + red[3];
  if (act) {
    float inv = 1.f / ss;
    out[(size_t)n * 1000 + j0] = e0 * inv;
    out[(size_t)n * 1000 + j0 + 1] = e1 * inv;
    out[(size_t)n * 1000 + j0 + 2] = e2 * inv;
    out[(size_t)n * 1000 + j0 + 3] = e3 * inv;
  }
}

extern "C" void kernel_launch(void* const* d_in, const int* in_sizes, int n_in, void* d_out,
                              int out_size, void* d_ws, size_t ws_size, hipStream_t stream) {
  const float* images = (const float*)d_in[0];
  const float* Wm = (const float*)d_in[1];
  const float* bm = (const float*)d_in[2];
  const float* cls_tok = (const float*)d_in[3];
  const float* pos_emb = (const float*)d_in[4];
  const float* ln1_w = (const float*)d_in[5];
  const float* ln1_b = (const float*)d_in[6];
  const float* Wq = (const float*)d_in[7];
  const float* bq = (const float*)d_in[8];
  const float* Wk = (const float*)d_in[9];
  const float* bk = (const float*)d_in[10];
  const float* Wv = (const float*)d_in[11];
  const float* bv = (const float*)d_in[12];
  const float* ln2_w = (const float*)d_in[13];
  const float* ln2_b = (const float*)d_in[14];
  const float* W1 = (const float*)d_in[15];
  const float* b1 = (const float*)d_in[16];
  const float* W2 = (const float*)d_in[17];
  const float* b2 = (const float*)d_in[18];
  const float* Wout = (const float*)d_in[19];
  const float* bout = (const float*)d_in[20];
  float* out = (float*)d_out;

  // --- workspace map ---
  // [0, 19.4M)        x            ND fp32
  // [19.4M, 38.7M)    hhi/hlo      2 x ND bf16
  // R = [38.7M, ...)  overlay:
  //   attn phase: q/k hi+lo (4xND bf16 = 38.7MB), vT hi+lo (2xVT = 25.2MB),
  //               wq hi+lo (0.6MB)  -> 64.5MB
  //   MLP phase:  ghi/glo (77.4MB); WB = R+77.4MB: w1/w2 hi+lo (18.9MB)
  char* base = (char*)d_ws;
  float* x = (float*)base;
  ushort_t* hhi = (ushort_t*)(base + (size_t)ND * 4);
  ushort_t* hlo = hhi + (size_t)ND;
  char* R = base + (size_t)ND * 8;
  ushort_t* qhi = (ushort_t*)R;
  ushort_t* qlo = qhi + (size_t)ND;
  ushort_t* khi = qlo + (size_t)ND;
  ushort_t* klo = khi + (size_t)ND;
  ushort_t* vthi = klo + (size_t)ND;
  ushort_t* vtlo = vthi + (size_t)VT_;
  ushort_t* wqhi = vtlo + (size_t)VT_;
  ushort_t* wqlo = wqhi + (size_t)3 * 12 * 64 * 64;
  ushort_t* ghi = (ushort_t*)R;
  ushort_t* glo = ghi + (size_t)MTOK * FF_;
  ushort_t* phi = (ushort_t*)R;
  ushort_t* plo = phi + (size_t)6272 * 768;
  char* WB = R + (size_t)MTOK * FF_ * 4;
  ushort_t* w1hi = (ushort_t*)WB;
  ushort_t* w1lo = w1hi + (size_t)768 * FF_;
  ushort_t* w2hi = w1lo + (size_t)768 * FF_;
  ushort_t* w2lo = w2hi + (size_t)768 * FF_;

  patchify_kernel<<<(6272 * 768 + 255) / 256, 256, 0, stream>>>(images, phi, plo);
  wconvert_kernel<<<dim3(24, 24), 256, 0, stream>>>(Wm, w1hi, w1lo, 768, 768);
  gemm_mfma<EPI_PATCH, 1><<<dim3(49, 6), 256, 0, stream>>>(phi, plo, w1hi, w1lo, bm, x,
                                                           nullptr, nullptr, 6272, 768, 768,
                                                           pos_emb);
  cls_init_kernel<<<(32 * 768) / 256, 256, 0, stream>>>(cls_tok, pos_emb, x);
  // zero vT once so the s>=197 pad stays 0.0 forever (qkv never writes pads)
  hipMemsetAsync(vthi, 0, (size_t)VT_ * 2 * sizeof(ushort_t), stream);

  for (int l = 0; l < 8; ++l) {
    ln_kernel<<<MTOK / 4, 256, 0, stream>>>(x, hhi, hlo, ln1_w + l * 768, ln1_b + l * 768);
    qkvw_convert<<<dim3(12, 3), 256, 0, stream>>>(Wq + (size_t)l * 49152,
                                                  Wk + (size_t)l * 49152,
                                                  Wv + (size_t)l * 49152, wqhi, wqlo);
    qkv_mfma<<<dim3(50, 12), 256, 0, stream>>>(hhi, hlo, wqhi, wqlo, bq + l * 768,
                                               bk + l * 768, bv + l * 768, qhi, qlo, khi, klo,
                                               vthi, vtlo);
    attn_mfma<<<dim3(4, 12, 32), 256, 0, stream>>>(qhi, qlo, khi, klo, vthi, vtlo, x);
    ln_kernel<<<MTOK / 4, 256, 0, stream>>>(x, hhi, hlo, ln2_w + l * 768, ln2_b + l * 768);
    wconvert_kernel<<<dim3(96, 24), 256, 0, stream>>>(W1 + (size_t)l * 768 * FF_, w1hi, w1lo,
                                                      768, FF_);
    gemm_mfma<EPI_GELU, 1><<<dim3(50, 24), 256, 0, stream>>>(hhi, hlo, w1hi, w1lo, b1 + l * FF_,
                                                             nullptr, ghi, glo, MTOK, 768, FF_,
                                                             nullptr);
    wconvert_kernel<<<dim3(24, 96), 256, 0, stream>>>(W2 + (size_t)l * FF_ * 768, w2hi, w2lo,
                                                      FF_, 768);
    // FC2 split-K=2: both halves atomically accumulate into x (z==0 adds bias)
    gemm_mfma<EPI_ATOM, 2><<<dim3(50, 6, 2), 256, 0, stream>>>(ghi, glo, w2hi, w2lo,
                                                               b2 + l * 768, x, nullptr,
                                                               nullptr, MTOK, FF_, 768,
                                                               nullptr);
  }
  head_kernel<<<32, 256, 0, stream>>>(x, Wout, bout, out);
}

// Round 6
// 3329.494 us; speedup vs baseline: 1.4461x; 1.1297x over previous
//
#include <hip/hip_runtime.h>
#include <math.h>

#define N_ 32
#define S_ 197
#define D_ 768
#define H_ 12
#define L_ 8
#define FF_ 3072
#define MTOK (N_ * S_)      // 6304
#define ND (N_ * S_ * D_)   // 4841472

typedef __attribute__((ext_vector_type(8))) short short8x;
typedef __attribute__((ext_vector_type(4))) float floatx4;
typedef unsigned short ushort_t;
typedef unsigned int uint_t;

__device__ __forceinline__ ushort_t f2bf_rn(float x) {
  uint_t u = __float_as_uint(x);
  uint_t r = (u + 0x7fff + ((u >> 16) & 1)) >> 16;
  return (ushort_t)r;
}
__device__ __forceinline__ float bf2f(ushort_t h) {
  return __uint_as_float(((uint_t)h) << 16);
}

// async global->LDS, 16B per lane, dest = wave-uniform base + lane*16
__device__ __forceinline__ void gload16(const ushort_t* g, ushort_t* l) {
  __builtin_amdgcn_global_load_lds((const __attribute__((address_space(1))) void*)g,
                                   (__attribute__((address_space(3))) void*)l, 16, 0, 0);
}

// ---------------- patchify ----------------
__global__ __launch_bounds__(256) void patchify_kernel(const float* __restrict__ img,
                                                       ushort_t* __restrict__ phi,
                                                       ushort_t* __restrict__ plo) {
  int idx = blockIdx.x * 256 + threadIdx.x;
  if (idx >= 6272 * 768) return;
  int mp = idx / 768, kk = idx - mp * 768;
  int n = mp / 196, p = mp - n * 196;
  int py = p / 14, px = p - py * 14;
  int c = kk >> 8, r = kk & 255;
  int u = r >> 4, vv = r & 15;
  float val = img[((size_t)(n * 3 + c) * 224 + py * 16 + u) * 224 + px * 16 + vv];
  ushort_t hi = f2bf_rn(val);
  phi[idx] = hi;
  plo[idx] = f2bf_rn(val - bf2f(hi));
}

__global__ __launch_bounds__(256) void cls_init_kernel(const float* __restrict__ cls_tok,
                                                       const float* __restrict__ pos,
                                                       float* __restrict__ x) {
  int idx = blockIdx.x * 256 + threadIdx.x;  // 32*768
  int n = idx / 768, d = idx - n * 768;
  x[(size_t)n * S_ * D_ + d] = cls_tok[d] + pos[d];
}

// ---------------- weight transpose + hi/lo split ----------------
__global__ __launch_bounds__(256) void wconvert_kernel(const float* __restrict__ W,
                                                       ushort_t* __restrict__ Thi,
                                                       ushort_t* __restrict__ Tlo, int K, int N) {
  __shared__ float T[32][36];
  int n0 = blockIdx.x * 32, k0 = blockIdx.y * 32;
  int t = threadIdx.x;
  int r = t >> 3, c4 = (t & 7) * 4;
  float4 v = *(const float4*)&W[(size_t)(k0 + r) * N + n0 + c4];
  T[c4 + 0][r] = v.x;
  T[c4 + 1][r] = v.y;
  T[c4 + 2][r] = v.z;
  T[c4 + 3][r] = v.w;
  __syncthreads();
  ushort4 hi, lo;
  float a;
  a = T[r][c4 + 0]; hi.x = f2bf_rn(a); lo.x = f2bf_rn(a - bf2f(hi.x));
  a = T[r][c4 + 1]; hi.y = f2bf_rn(a); lo.y = f2bf_rn(a - bf2f(hi.y));
  a = T[r][c4 + 2]; hi.z = f2bf_rn(a); lo.z = f2bf_rn(a - bf2f(hi.z));
  a = T[r][c4 + 3]; hi.w = f2bf_rn(a); lo.w = f2bf_rn(a - bf2f(hi.w));
  size_t o = (size_t)(n0 + r) * K + k0 + c4;
  *(ushort4*)&Thi[o] = hi;
  *(ushort4*)&Tlo[o] = lo;
}

// ---------------- QKV weight pre-convert: W[h][k][col] -> Wt[mat][h][col][k] hi/lo ---
__global__ __launch_bounds__(256) void qkvw_convert(const float* __restrict__ Wq,
                                                    const float* __restrict__ Wk,
                                                    const float* __restrict__ Wv,
                                                    ushort_t* __restrict__ wthi,
                                                    ushort_t* __restrict__ wtlo) {
  __shared__ float T[64][65];
  int h = blockIdx.x, mat = blockIdx.y;
  const float* W = (mat == 0 ? Wq : mat == 1 ? Wk : Wv) + (size_t)h * 4096;
  int tid = threadIdx.x;
  int r = tid >> 2, c0 = (tid & 3) * 16;
#pragma unroll
  for (int i = 0; i < 4; ++i) {
    float4 v = *(const float4*)&W[r * 64 + c0 + i * 4];
    T[c0 + i * 4 + 0][r] = v.x;
    T[c0 + i * 4 + 1][r] = v.y;
    T[c0 + i * 4 + 2][r] = v.z;
    T[c0 + i * 4 + 3][r] = v.w;
  }
  __syncthreads();
  size_t base = (((size_t)mat * 12 + h) * 64 + r) * 64 + c0;  // Wt[col=r][k]
#pragma unroll
  for (int i = 0; i < 4; ++i) {
    ushort4 hi4, lo4;
    float a;
    a = T[r][c0 + i * 4 + 0]; hi4.x = f2bf_rn(a); lo4.x = f2bf_rn(a - bf2f(hi4.x));
    a = T[r][c0 + i * 4 + 1]; hi4.y = f2bf_rn(a); lo4.y = f2bf_rn(a - bf2f(hi4.y));
    a = T[r][c0 + i * 4 + 2]; hi4.z = f2bf_rn(a); lo4.z = f2bf_rn(a - bf2f(hi4.z));
    a = T[r][c0 + i * 4 + 3]; hi4.w = f2bf_rn(a); lo4.w = f2bf_rn(a - bf2f(hi4.w));
    *(ushort4*)&wthi[base + i * 4] = hi4;
    *(ushort4*)&wtlo[base + i * 4] = lo4;
  }
}

// ---------------- split-bf16 MFMA GEMM (R0k structure: best measured TOTAL) ----------
// 32KB single-buffered LDS -> 5 blocks/CU; inter-block TLP hides load latency
// (double/triple-buffer variants measured worse on total despite faster FC1).
// Staging: global_load_lds (16B/lane), linear LDS rows of 32 ushorts.
// Source-side chunk swizzle c ^= (row>>1)&3 (16B chunks), same XOR on ds_read
// addresses -> conflict-free b128 reads without padding.
// EPI_ATOM (KP=2): both K-halves unsafeAtomicAdd into Cf (z==0 adds bias).
#define EPI_PATCH 1
#define EPI_GELU 2
#define EPI_ATOM 3

template <int EPI, int KP>
__global__ __launch_bounds__(256) void gemm_mfma(
    const ushort_t* __restrict__ Ahi, const ushort_t* __restrict__ Alo,
    const ushort_t* __restrict__ Bhi, const ushort_t* __restrict__ Blo,
    const float* __restrict__ bias, float* __restrict__ Cf, ushort_t* __restrict__ Chi,
    ushort_t* __restrict__ Clo, int M, int K, int Nc, const float* __restrict__ pos) {
  __shared__ ushort_t As[2][128 * 32];   // hi/lo planes, 8KB each
  __shared__ ushort_t Bs[2][128 * 32];
  int tid = threadIdx.x;
  int wave = tid >> 6, lane = tid & 63;
  int wr = (wave >> 1) * 64, wc = (wave & 1) * 64;
  int q = lane >> 4, l15 = lane & 15;
  int m0 = blockIdx.x * 128, n0 = blockIdx.y * 128;
  int kbeg = (KP > 1) ? blockIdx.z * (K / KP) : 0;
  int kend = kbeg + K / KP;

  floatx4 acc[4][4];
#pragma unroll
  for (int i = 0; i < 4; ++i)
#pragma unroll
    for (int j = 0; j < 4; ++j)
#pragma unroll
      for (int e = 0; e < 4; ++e) acc[i][j][e] = 0.f;

  // staging geometry: wave stages rows [wave*32, wave*32+32), 16 rows/instr
  int srow_in = lane >> 2;                 // 0..15 within instr
  int schunk = lane & 3;                   // 16B chunk within row
  // fragment read swizzle (row bits 1-2 come from l15 only)
  int csw = (q ^ ((l15 >> 1) & 3)) * 8;

  for (int k0 = kbeg; k0 < kend; k0 += 32) {
#pragma unroll
    for (int j = 0; j < 2; ++j) {
      int rbase = (wave << 5) + (j << 4);
      int r = rbase + srow_in;
      int cc = schunk ^ ((r >> 1) & 3);    // pre-swizzled source chunk
      int gm = m0 + r;
      if (gm > M - 1) gm = M - 1;
      size_t aoff = (size_t)gm * K + k0 + cc * 8;
      size_t boff = (size_t)(n0 + r) * K + k0 + cc * 8;
      gload16(&Ahi[aoff], &As[0][rbase * 32]);
      gload16(&Alo[aoff], &As[1][rbase * 32]);
      gload16(&Bhi[boff], &Bs[0][rbase * 32]);
      gload16(&Blo[boff], &Bs[1][rbase * 32]);
    }
    asm volatile("s_waitcnt vmcnt(0)" ::: "memory");
    __syncthreads();

    short8x ah[4], al[4], bh[4], bl[4];
#pragma unroll
    for (int i = 0; i < 4; ++i) {
      int ao = (wr + i * 16 + l15) * 32 + csw;
      int bo = (wc + i * 16 + l15) * 32 + csw;
      ah[i] = *(const short8x*)&As[0][ao];
      al[i] = *(const short8x*)&As[1][ao];
      bh[i] = *(const short8x*)&Bs[0][bo];
      bl[i] = *(const short8x*)&Bs[1][bo];
    }
#pragma unroll
    for (int i = 0; i < 4; ++i)
#pragma unroll
      for (int j = 0; j < 4; ++j) {
        acc[i][j] = __builtin_amdgcn_mfma_f32_16x16x32_bf16(ah[i], bh[j], acc[i][j], 0, 0, 0);
        acc[i][j] = __builtin_amdgcn_mfma_f32_16x16x32_bf16(ah[i], bl[j], acc[i][j], 0, 0, 0);
        acc[i][j] = __builtin_amdgcn_mfma_f32_16x16x32_bf16(al[i], bh[j], acc[i][j], 0, 0, 0);
      }
    __syncthreads();
  }

#pragma unroll
  for (int i = 0; i < 4; ++i) {
#pragma unroll
    for (int j = 0; j < 4; ++j) {
      int col = n0 + wc + j * 16 + l15;
#pragma unroll
      for (int r4 = 0; r4 < 4; ++r4) {
        int gr = m0 + wr + i * 16 + q * 4 + r4;
        if (gr >= M) continue;
        if (EPI == EPI_ATOM) {
          float v = acc[i][j][r4];
          if (KP == 1 || blockIdx.z == 0) v += bias[col];
          unsafeAtomicAdd(&Cf[(size_t)gr * 768 + col], v);
        } else {
          float v = acc[i][j][r4] + bias[col];
          if (EPI == EPI_PATCH) {
            int n = gr / 196, t = gr - n * 196 + 1;
            Cf[((size_t)n * S_ + t) * 768 + col] = v + pos[(size_t)t * 768 + col];
          } else {  // EPI_GELU
            float g = 0.5f * v * (1.f + erff(v * 0.70710678118654752f));
            ushort_t hi = f2bf_rn(g);
            size_t o = (size_t)gr * FF_ + col;
            Chi[o] = hi;
            Clo[o] = f2bf_rn(g - bf2f(hi));
          }
        }
      }
    }
  }
}

// ---------------- LayerNorm -> bf16 hi/lo ----------------
__global__ __launch_bounds__(256) void ln_kernel(const float* __restrict__ x,
                                                 ushort_t* __restrict__ hhi,
                                                 ushort_t* __restrict__ hlo,
                                                 const float* __restrict__ w,
                                                 const float* __restrict__ b) {
  int tok = blockIdx.x * 4 + (threadIdx.x >> 6);
  int lane = threadIdx.x & 63;
  const float* xr = x + (size_t)tok * 768;
  float4 v[3];
  float s = 0.f, s2 = 0.f;
#pragma unroll
  for (int i = 0; i < 3; ++i) {
    v[i] = *(const float4*)&xr[i * 256 + lane * 4];
    s += v[i].x + v[i].y + v[i].z + v[i].w;
    s2 += v[i].x * v[i].x + v[i].y * v[i].y + v[i].z * v[i].z + v[i].w * v[i].w;
  }
#pragma unroll
  for (int m = 32; m > 0; m >>= 1) { s += __shfl_xor(s, m, 64); s2 += __shfl_xor(s2, m, 64); }
  float mu = s * (1.f / 768.f);
  float var = s2 * (1.f / 768.f) - mu * mu;
  float rs = rsqrtf(var + 1e-5f);
#pragma unroll
  for (int i = 0; i < 3; ++i) {
    float4 wv = *(const float4*)&w[i * 256 + lane * 4];
    float4 bv = *(const float4*)&b[i * 256 + lane * 4];
    float o0 = (v[i].x - mu) * rs * wv.x + bv.x;
    float o1 = (v[i].y - mu) * rs * wv.y + bv.y;
    float o2 = (v[i].z - mu) * rs * wv.z + bv.z;
    float o3 = (v[i].w - mu) * rs * wv.w + bv.w;
    ushort4 oh, ol;
    oh.x = f2bf_rn(o0); ol.x = f2bf_rn(o0 - bf2f(oh.x));
    oh.y = f2bf_rn(o1); ol.y = f2bf_rn(o1 - bf2f(oh.y));
    oh.z = f2bf_rn(o2); ol.z = f2bf_rn(o2 - bf2f(oh.z));
    oh.w = f2bf_rn(o3); ol.w = f2bf_rn(o3 - bf2f(oh.w));
    size_t o = (size_t)tok * 768 + i * 256 + lane * 4;
    *(ushort4*)&hhi[o] = oh;
    *(ushort4*)&hlo[o] = ol;
  }
}

// ---------------- QKV projection via MFMA: block = 128 tokens x head ----------------
// W fragments read DIRECTLY from pre-converted Wt[mat][h][col][k] (global->reg,
// L2-resident 147KB/layer; removes 12K f2bf VALU + 6 barriers per block).
// Q/K/V outputs in original coalesced tok-major layout.
#define KSTR 72

__global__ __launch_bounds__(256) void qkv_mfma(
    const ushort_t* __restrict__ hhi, const ushort_t* __restrict__ hlo,
    const ushort_t* __restrict__ wthi, const ushort_t* __restrict__ wtlo,
    const float* __restrict__ bq, const float* __restrict__ bk, const float* __restrict__ bv,
    ushort_t* __restrict__ qhi, ushort_t* __restrict__ qlo, ushort_t* __restrict__ khi,
    ushort_t* __restrict__ klo, ushort_t* __restrict__ vhi, ushort_t* __restrict__ vlo) {
  __shared__ ushort_t As[2][128 * KSTR];
  int tid = threadIdx.x;
  int wave = tid >> 6, lane = tid & 63;
  int q = lane >> 4, l15 = lane & 15;
  int m0 = blockIdx.x * 128, h = blockIdx.y;
  int wm = wave >> 1, wj = wave & 1;

#pragma unroll
  for (int p = 0; p < 2; ++p) {
    const ushort_t* src = p == 0 ? hhi : hlo;
#pragma unroll
    for (int it = 0; it < 4; ++it) {
      int idx = it * 256 + tid;
      int r = idx >> 3, c = idx & 7;
      int gm = m0 + r;
      if (gm > MTOK - 1) gm = MTOK - 1;
      *(uint4*)&As[p][r * KSTR + c * 8] = *(const uint4*)&src[(size_t)gm * 768 + h * 64 + c * 8];
    }
  }
  __syncthreads();

  const float* Bmat[3] = {bq + h * 64, bk + h * 64, bv + h * 64};
  ushort_t* Ohi[3] = {qhi, khi, vhi};
  ushort_t* Olo[3] = {qlo, klo, vlo};

  for (int mat = 0; mat < 3; ++mat) {
    const ushort_t* wh = wthi + ((size_t)mat * 12 + h) * 4096;
    const ushort_t* wl = wtlo + ((size_t)mat * 12 + h) * 4096;
    short8x bh[2][2], bl[2][2];  // [ks][j]
#pragma unroll
    for (int ks = 0; ks < 2; ++ks)
#pragma unroll
      for (int j = 0; j < 2; ++j) {
        int wo = (wj * 32 + j * 16 + l15) * 64 + ks * 32 + q * 8;
        bh[ks][j] = *(const short8x*)&wh[wo];
        bl[ks][j] = *(const short8x*)&wl[wo];
      }

    floatx4 acc[4][2];
#pragma unroll
    for (int i = 0; i < 4; ++i)
#pragma unroll
      for (int j = 0; j < 2; ++j)
#pragma unroll
        for (int e = 0; e < 4; ++e) acc[i][j][e] = 0.f;

#pragma unroll
    for (int ks = 0; ks < 2; ++ks) {
#pragma unroll
      for (int i = 0; i < 4; ++i) {
        int ab = (wm * 64 + i * 16 + l15) * KSTR + ks * 32 + q * 8;
        short8x ah = *(const short8x*)&As[0][ab];
        short8x al = *(const short8x*)&As[1][ab];
#pragma unroll
        for (int j = 0; j < 2; ++j) {
          acc[i][j] = __builtin_amdgcn_mfma_f32_16x16x32_bf16(ah, bh[ks][j], acc[i][j], 0, 0, 0);
          acc[i][j] = __builtin_amdgcn_mfma_f32_16x16x32_bf16(ah, bl[ks][j], acc[i][j], 0, 0, 0);
          acc[i][j] = __builtin_amdgcn_mfma_f32_16x16x32_bf16(al, bh[ks][j], acc[i][j], 0, 0, 0);
        }
      }
    }
#pragma unroll
    for (int i = 0; i < 4; ++i)
#pragma unroll
      for (int j = 0; j < 2; ++j) {
        int col = wj * 32 + j * 16 + l15;
        float bias = Bmat[mat][col];
#pragma unroll
        for (int r = 0; r < 4; ++r) {
          int tok = m0 + wm * 64 + i * 16 + q * 4 + r;
          if (tok >= MTOK) continue;
          float v = acc[i][j][r] + bias;
          ushort_t hi = f2bf_rn(v);
          size_t o = (size_t)tok * 768 + h * 64 + col;
          Ohi[mat][o] = hi;
          Olo[mat][o] = f2bf_rn(v - bf2f(hi));
        }
      }
  }
}

// ---------------- MFMA flash attention ----------------
__global__ __launch_bounds__(256) void attn_mfma(
    const ushort_t* __restrict__ qhi, const ushort_t* __restrict__ qlo,
    const ushort_t* __restrict__ khi, const ushort_t* __restrict__ klo,
    const ushort_t* __restrict__ vhi, const ushort_t* __restrict__ vlo,
    float* __restrict__ X) {
  __shared__ ushort_t Qs[2][64 * KSTR];
  __shared__ ushort_t Ks[2][64 * KSTR];
  __shared__ ushort_t Vs[2][64 * KSTR];
  int tid = threadIdx.x;
  int wave = tid >> 6, lane = tid & 63;
  int q = lane >> 4, l15 = lane & 15;
  int qc = blockIdx.x, h = blockIdx.y, n = blockIdx.z;
  int q0 = qc * 64;
  int row0 = wave * 16;

#pragma unroll
  for (int p = 0; p < 2; ++p) {
    const ushort_t* src = p == 0 ? qhi : qlo;
#pragma unroll
    for (int it = 0; it < 2; ++it) {
      int idx = it * 256 + tid;
      int r = idx >> 3, c = idx & 7;
      int gr = q0 + r;
      if (gr > S_ - 1) gr = S_ - 1;
      *(uint4*)&Qs[p][r * KSTR + c * 8] =
          *(const uint4*)&src[((size_t)n * S_ + gr) * 768 + h * 64 + c * 8];
    }
  }
  __syncthreads();
  short8x qa_h[2], qa_l[2];
#pragma unroll
  for (int ks = 0; ks < 2; ++ks) {
    int ab = (row0 + l15) * KSTR + ks * 32 + q * 8;
    qa_h[ks] = *(const short8x*)&Qs[0][ab];
    qa_l[ks] = *(const short8x*)&Qs[1][ab];
  }

  float mrow[4], lrow[4];
  floatx4 oa[4];
#pragma unroll
  for (int r = 0; r < 4; ++r) { mrow[r] = -INFINITY; lrow[r] = 0.f; }
#pragma unroll
  for (int j = 0; j < 4; ++j)
#pragma unroll
    for (int e = 0; e < 4; ++e) oa[j][e] = 0.f;

  for (int t = 0; t < 4; ++t) {
    __syncthreads();
#pragma unroll
    for (int p = 0; p < 2; ++p) {
      const ushort_t* src = p == 0 ? khi : klo;
#pragma unroll
      for (int it = 0; it < 2; ++it) {
        int idx = it * 256 + tid;
        int r = idx >> 3, c = idx & 7;
        int gk = t * 64 + r;
        if (gk > S_ - 1) gk = S_ - 1;
        *(uint4*)&Ks[p][r * KSTR + c * 8] =
            *(const uint4*)&src[((size_t)n * S_ + gk) * 768 + h * 64 + c * 8];
      }
    }
    {
      int d = tid & 63, kg = tid >> 6;
#pragma unroll
      for (int p = 0; p < 2; ++p) {
        const ushort_t* src = p == 0 ? vhi : vlo;
#pragma unroll
        for (int k4 = 0; k4 < 4; ++k4) {
          ushort4 pk;
          ushort_t tmp[4];
#pragma unroll
          for (int i = 0; i < 4; ++i) {
            int gk = t * 64 + kg * 16 + k4 * 4 + i;
            if (gk > S_ - 1) gk = S_ - 1;
            tmp[i] = src[((size_t)n * S_ + gk) * 768 + h * 64 + d];
          }
          pk.x = tmp[0]; pk.y = tmp[1]; pk.z = tmp[2]; pk.w = tmp[3];
          *(ushort4*)&Vs[p][d * KSTR + kg * 16 + k4 * 4] = pk;
        }
      }
    }
    __syncthreads();

    floatx4 sc[4];
#pragma unroll
    for (int j = 0; j < 4; ++j) {
#pragma unroll
      for (int e = 0; e < 4; ++e) sc[j][e] = 0.f;
#pragma unroll
      for (int ks = 0; ks < 2; ++ks) {
        int bb = (j * 16 + l15) * KSTR + ks * 32 + q * 8;
        short8x kb_h = *(const short8x*)&Ks[0][bb];
        short8x kb_l = *(const short8x*)&Ks[1][bb];
        sc[j] = __builtin_amdgcn_mfma_f32_16x16x32_bf16(qa_h[ks], kb_h, sc[j], 0, 0, 0);
        sc[j] = __builtin_amdgcn_mfma_f32_16x16x32_bf16(qa_h[ks], kb_l, sc[j], 0, 0, 0);
        sc[j] = __builtin_amdgcn_mfma_f32_16x16x32_bf16(qa_l[ks], kb_h, sc[j], 0, 0, 0);
      }
    }
    __syncthreads();

    bool kvalid[4];
#pragma unroll
    for (int j = 0; j < 4; ++j) kvalid[j] = (t * 64 + j * 16 + l15) < S_;
#pragma unroll
    for (int r = 0; r < 4; ++r) {
      float sv[4];
#pragma unroll
      for (int j = 0; j < 4; ++j) sv[j] = kvalid[j] ? sc[j][r] * 0.125f : -INFINITY;
      float mx = fmaxf(fmaxf(sv[0], sv[1]), fmaxf(sv[2], sv[3]));
#pragma unroll
      for (int msk = 1; msk < 16; msk <<= 1) mx = fmaxf(mx, __shfl_xor(mx, msk, 64));
      float mn = fmaxf(mrow[r], mx);
      float al = expf(mrow[r] - mn);
      float p[4], ps = 0.f;
#pragma unroll
      for (int j = 0; j < 4; ++j) { p[j] = expf(sv[j] - mn); ps += p[j]; }
#pragma unroll
      for (int msk = 1; msk < 16; msk <<= 1) ps += __shfl_xor(ps, msk, 64);
      lrow[r] = lrow[r] * al + ps;
      mrow[r] = mn;
#pragma unroll
      for (int j = 0; j < 4; ++j) oa[j][r] *= al;
      int prow = (row0 + q * 4 + r) * KSTR;
#pragma unroll
      for (int j = 0; j < 4; ++j) {
        ushort_t phv = f2bf_rn(p[j]);
        Ks[0][prow + j * 16 + l15] = phv;
        Ks[1][prow + j * 16 + l15] = f2bf_rn(p[j] - bf2f(phv));
      }
    }

#pragma unroll
    for (int ks = 0; ks < 2; ++ks) {
      int ab = (row0 + l15) * KSTR + ks * 32 + q * 8;
      short8x pa_h = *(const short8x*)&Ks[0][ab];
      short8x pa_l = *(const short8x*)&Ks[1][ab];
#pragma unroll
      for (int j = 0; j < 4; ++j) {
        int bb = (j * 16 + l15) * KSTR + ks * 32 + q * 8;
        short8x vb_h = *(const short8x*)&Vs[0][bb];
        short8x vb_l = *(const short8x*)&Vs[1][bb];
        oa[j] = __builtin_amdgcn_mfma_f32_16x16x32_bf16(pa_h, vb_h, oa[j], 0, 0, 0);
        oa[j] = __builtin_amdgcn_mfma_f32_16x16x32_bf16(pa_h, vb_l, oa[j], 0, 0, 0);
        oa[j] = __builtin_amdgcn_mfma_f32_16x16x32_bf16(pa_l, vb_h, oa[j], 0, 0, 0);
      }
    }
  }

#pragma unroll
  for (int r = 0; r < 4; ++r) {
    int row = q0 + row0 + q * 4 + r;
    if (row >= S_) continue;
    float invl = 1.f / lrow[r];
#pragma unroll
    for (int j = 0; j < 4; ++j)
      X[((size_t)n * S_ + row) * 768 + h * 64 + j * 16 + l15] += oa[j][r] * invl;
  }
}

// ---------------- classifier head + softmax ----------------
__global__ __launch_bounds__(256) void head_kernel(const float* __restrict__ x,
                                                   const float* __restrict__ Wout,
                                                   const float* __restrict__ bout,
                                                   float* __restrict__ out) {
  __shared__ float cls[768];
  __shared__ float red[4];
  int n = blockIdx.x, tid = threadIdx.x;
  int w = tid >> 6, lane = tid & 63;
  for (int d = tid; d < 768; d += 256) cls[d] = x[(size_t)n * S_ * D_ + d];
  __syncthreads();
  int j0 = tid * 4;
  bool act = j0 < 1000;
  float a0 = 0.f, a1 = 0.f, a2 = 0.f, a3 = 0.f;
  if (act) {
    for (int kk = 0; kk < 768; ++kk) {
      float c = cls[kk];
      float4 wv = *(const float4*)&Wout[(size_t)kk * 1000 + j0];
      a0 += c * wv.x;
      a1 += c * wv.y;
      a2 += c * wv.z;
      a3 += c * wv.w;
    }
    a0 += bout[j0];
    a1 += bout[j0 + 1];
    a2 += bout[j0 + 2];
    a3 += bout[j0 + 3];
  }
  float mx = act ? fmaxf(fmaxf(a0, a1), fmaxf(a2, a3)) : -INFINITY;
#pragma unroll
  for (int m = 32; m > 0; m >>= 1) mx = fmaxf(mx, __shfl_xor(mx, m, 64));
  if (lane == 0) red[w] = mx;
  __syncthreads();
  mx = fmaxf(fmaxf(red[0], red[1]), fmaxf(red[2], red[3]));
  __syncthreads();
  float e0 = 0.f, e1 = 0.f, e2 = 0.f, e3 = 0.f, ss = 0.f;
  if (act) {
    e0 = expf(a0 - mx);
    e1 = expf(a1 - mx);
    e2 = expf(a2 - mx);
    e3 = expf(a3 - mx);
    ss = e0 + e1 + e2 + e3;
  }
#pragma unroll
  for (int m = 32; m > 0; m >>= 1) ss += __shfl_xor(ss, m, 64);
  if (lane == 0) red[w] = ss;
  __syncthreads();
  ss = red[0] + red[1] + red[2] + red[3];
  if (act) {
    float inv = 1.f / ss;
    out[(size_t)n * 1000 + j0] = e0 * inv;
    out[(size_t)n * 1000 + j0 + 1] = e1 * inv;
    out[(size_t)n * 1000 + j0 + 2] = e2 * inv;
    out[(size_t)n * 1000 + j0 + 3] = e3 * inv;
  }
}

extern "C" void kernel_launch(void* const* d_in, const int* in_sizes, int n_in, void* d_out,
                              int out_size, void* d_ws, size_t ws_size, hipStream_t stream) {
  const float* images = (const float*)d_in[0];
  const float* Wm = (const float*)d_in[1];
  const float* bm = (const float*)d_in[2];
  const float* cls_tok = (const float*)d_in[3];
  const float* pos_emb = (const float*)d_in[4];
  const float* ln1_w = (const float*)d_in[5];
  const float* ln1_b = (const float*)d_in[6];
  const float* Wq = (const float*)d_in[7];
  const float* bq = (const float*)d_in[8];
  const float* Wk = (const float*)d_in[9];
  const float* bk = (const float*)d_in[10];
  const float* Wv = (const float*)d_in[11];
  const float* bv = (const float*)d_in[12];
  const float* ln2_w = (const float*)d_in[13];
  const float* ln2_b = (const float*)d_in[14];
  const float* W1 = (const float*)d_in[15];
  const float* b1 = (const float*)d_in[16];
  const float* W2 = (const float*)d_in[17];
  const float* b2 = (const float*)d_in[18];
  const float* Wout = (const float*)d_in[19];
  const float* bout = (const float*)d_in[20];
  float* out = (float*)d_out;

  // --- workspace map (proven-fit layout) ---
  // [0, 19.4M)        x            ND fp32
  // [19.4M, 38.7M)    hhi/hlo      2 x ND bf16
  // R = [38.7M, ...)  overlay:
  //   attn phase: q/k/v hi+lo (6xND bf16 = 58.1MB) + wq hi/lo (1.2MB at R+58.1M)
  //   MLP phase:  ghi/glo (77.4MB) -- clobbers wq, re-converted each layer
  //   WB = R+77.4M: w1/w2 hi+lo (18.9MB)
  char* base = (char*)d_ws;
  float* x = (float*)base;
  ushort_t* hhi = (ushort_t*)(base + (size_t)ND * 4);
  ushort_t* hlo = hhi + (size_t)ND;
  char* R = base + (size_t)ND * 8;
  ushort_t* qhi = (ushort_t*)R;
  ushort_t* qlo = qhi + (size_t)ND;
  ushort_t* khi = qlo + (size_t)ND;
  ushort_t* klo = khi + (size_t)ND;
  ushort_t* vhi = klo + (size_t)ND;
  ushort_t* vlo = vhi + (size_t)ND;
  ushort_t* wqhi = vlo + (size_t)ND;
  ushort_t* wqlo = wqhi + (size_t)3 * 12 * 64 * 64;
  ushort_t* ghi = (ushort_t*)R;
  ushort_t* glo = ghi + (size_t)MTOK * FF_;
  ushort_t* phi = (ushort_t*)R;
  ushort_t* plo = phi + (size_t)6272 * 768;
  char* WB = R + (size_t)MTOK * FF_ * 4;
  ushort_t* w1hi = (ushort_t*)WB;
  ushort_t* w1lo = w1hi + (size_t)768 * FF_;
  ushort_t* w2hi = w1lo + (size_t)768 * FF_;
  ushort_t* w2lo = w2hi + (size_t)768 * FF_;

  patchify_kernel<<<(6272 * 768 + 255) / 256, 256, 0, stream>>>(images, phi, plo);
  wconvert_kernel<<<dim3(24, 24), 256, 0, stream>>>(Wm, w1hi, w1lo, 768, 768);
  gemm_mfma<EPI_PATCH, 1><<<dim3(49, 6), 256, 0, stream>>>(phi, plo, w1hi, w1lo, bm, x,
                                                           nullptr, nullptr, 6272, 768, 768,
                                                           pos_emb);
  cls_init_kernel<<<(32 * 768) / 256, 256, 0, stream>>>(cls_tok, pos_emb, x);

  for (int l = 0; l < 8; ++l) {
    ln_kernel<<<MTOK / 4, 256, 0, stream>>>(x, hhi, hlo, ln1_w + l * 768, ln1_b + l * 768);
    qkvw_convert<<<dim3(12, 3), 256, 0, stream>>>(Wq + (size_t)l * 49152,
                                                  Wk + (size_t)l * 49152,
                                                  Wv + (size_t)l * 49152, wqhi, wqlo);
    qkv_mfma<<<dim3(50, 12), 256, 0, stream>>>(hhi, hlo, wqhi, wqlo, bq + l * 768,
                                               bk + l * 768, bv + l * 768, qhi, qlo, khi, klo,
                                               vhi, vlo);
    attn_mfma<<<dim3(4, 12, 32), 256, 0, stream>>>(qhi, qlo, khi, klo, vhi, vlo, x);
    ln_kernel<<<MTOK / 4, 256, 0, stream>>>(x, hhi, hlo, ln2_w + l * 768, ln2_b + l * 768);
    wconvert_kernel<<<dim3(96, 24), 256, 0, stream>>>(W1 + (size_t)l * 768 * FF_, w1hi, w1lo,
                                                      768, FF_);
    gemm_mfma<EPI_GELU, 1><<<dim3(50, 24), 256, 0, stream>>>(hhi, hlo, w1hi, w1lo, b1 + l * FF_,
                                                             nullptr, ghi, glo, MTOK, 768, FF_,
                                                             nullptr);
    wconvert_kernel<<<dim3(24, 96), 256, 0, stream>>>(W2 + (size_t)l * FF_ * 768, w2hi, w2lo,
                                                      FF_, 768);
    // FC2 split-K=2: both halves atomically accumulate into x (z==0 adds bias)
    gemm_mfma<EPI_ATOM, 2><<<dim3(50, 6, 2), 256, 0, stream>>>(ghi, glo, w2hi, w2lo,
                                                               b2 + l * 768, x, nullptr,
                                                               nullptr, MTOK, FF_, 768,
                                                               nullptr);
  }
  head_kernel<<<32, 256, 0, stream>>>(x, Wout, bout, out);
}